// Round 2
// baseline (1124.189 us; speedup 1.0000x reference)
//
#include <hip/hip_runtime.h>

#define EPS 1e-5f
constexpr int NN = 4096;
constexpr float INV_CNT = 1.0f / (8.0f * 4096.0f);

// workspace layout (float offsets)
constexpr size_t OFF_QP  = 0;        // 8*16*4096 = 524288
constexpr size_t OFF_KP  = 524288;   // 524288
constexpr size_t OFF_VP  = 1048576;  // 8*3*4096 = 98304
constexpr size_t OFF_ST  = 1146880;  // 256 stats: [0..8] x-moments; [128..197] qkv stats
constexpr size_t OFF_PR  = 1147136;  // 256: [128..197] BN2/3/4 scale/shift
constexpr size_t OFF_W1P = 1147392;  // 256: per-channel {w0*sc, w1*sc, w2*sc, shift}

__device__ __forceinline__ void red16_2(float& s, float& q) {
  #pragma unroll
  for (int off = 1; off <= 8; off <<= 1) { s += __shfl_xor(s, off); q += __shfl_xor(q, off); }
}

// ---- K0: x first/second moments (9 scalars) --------------------------------
__global__ __launch_bounds__(256) void k0_xmom(const float* __restrict__ x,
                                               float* __restrict__ st) {
  int idx = blockIdx.x * 256 + threadIdx.x;
  int b = idx >> 12, n = idx & 4095;
  float x0 = x[(size_t)(b*3+0)*NN + n];
  float x1 = x[(size_t)(b*3+1)*NN + n];
  float x2 = x[(size_t)(b*3+2)*NN + n];
  float m[9] = {x0, x1, x2, x0*x0, x0*x1, x0*x2, x1*x1, x1*x2, x2*x2};
  #pragma unroll
  for (int off = 32; off; off >>= 1) {
    #pragma unroll
    for (int j = 0; j < 9; ++j) m[j] += __shfl_xor(m[j], off);
  }
  if ((threadIdx.x & 63) == 0) {
    #pragma unroll
    for (int j = 0; j < 9; ++j) atomicAdd(&st[j], m[j]);
  }
}

// ---- F1: analytic BN1 params, folded into w1 -------------------------------
__global__ void f1_fin(const float* __restrict__ st, const float* __restrict__ w1,
                       const float* __restrict__ g1, const float* __restrict__ b1,
                       float* __restrict__ w1p) {
  int c = threadIdx.x;  // 64
  float mx0 = st[0]*INV_CNT, mx1 = st[1]*INV_CNT, mx2 = st[2]*INV_CNT;
  float M00 = st[3]*INV_CNT, M01 = st[4]*INV_CNT, M02 = st[5]*INV_CNT;
  float M11 = st[6]*INV_CNT, M12 = st[7]*INV_CNT, M22 = st[8]*INV_CNT;
  float a = w1[c*3], b_ = w1[c*3+1], d = w1[c*3+2];
  float mean = a*mx0 + b_*mx1 + d*mx2;
  float e2 = a*a*M00 + b_*b_*M11 + d*d*M22 + 2.f*(a*b_*M01 + a*d*M02 + b_*d*M12);
  float sc = g1[c] * rsqrtf(e2 - mean*mean + EPS);
  w1p[c*4+0] = a*sc; w1p[c*4+1] = b_*sc; w1p[c*4+2] = d*sc;
  w1p[c*4+3] = fmaf(-mean, sc, b1[c]);
}

// ---- K3: x -> h (BN1+LReLU) -> feat -> q/k/v pre + stats -------------------
// 4 threads per point split the 128 o's (o = 4*oo + sl), shfl-combine.
__global__ __launch_bounds__(256) void k3_feat_qkv(
    const float* __restrict__ x, const float* __restrict__ w2,
    const float* __restrict__ wq, const float* __restrict__ wk,
    const float* __restrict__ wv, const float* __restrict__ w1p,
    float* __restrict__ qp, float* __restrict__ kp, float* __restrict__ vp,
    float* __restrict__ st) {
  __shared__ float4 w2s[128*17];   // row-pad 17 -> conflict-free for o-delta 1
  __shared__ float4 wts[128*9];    // [o][{q0..3,k0..3,v}] transposed
  __shared__ float4 w1s[64];
  int tx = threadIdx.x;
  const float4* w2g = (const float4*)w2;
  for (int i = tx; i < 2048; i += 256) w2s[(i >> 4)*17 + (i & 15)] = w2g[i];
  for (int i = tx; i < 1152; i += 256) {
    int o = i / 9, j = i - o*9;
    float4 t;
    if (j < 4)      t = make_float4(wq[(4*j)*128+o], wq[(4*j+1)*128+o], wq[(4*j+2)*128+o], wq[(4*j+3)*128+o]);
    else if (j < 8) t = make_float4(wk[(4*j-16)*128+o], wk[(4*j-15)*128+o], wk[(4*j-14)*128+o], wk[(4*j-13)*128+o]);
    else            t = make_float4(wv[o], wv[128+o], wv[256+o], 0.f);
    wts[i] = t;
  }
  if (tx < 64) w1s[tx] = ((const float4*)w1p)[tx];
  __syncthreads();

  int l = tx & 63;
  int sl = l >> 4;                       // o-slice 0..3
  int idx = blockIdx.x*64 + (tx >> 6)*16 + (l & 15);
  int b = idx >> 12, n = idx & 4095;
  float x0 = x[(size_t)(b*3+0)*NN + n];
  float x1 = x[(size_t)(b*3+1)*NN + n];
  float x2 = x[(size_t)(b*3+2)*NN + n];
  float hreg[64];
  #pragma unroll
  for (int c = 0; c < 64; ++c) {
    float4 w = w1s[c];
    float v = fmaf(w.x, x0, fmaf(w.y, x1, fmaf(w.z, x2, w.w)));
    hreg[c] = v > 0.f ? v : 0.2f*v;
  }
  float qa[16] = {}, ka[16] = {};
  float va0 = 0.f, va1 = 0.f, va2 = 0.f;
  #pragma unroll 2
  for (int oo = 0; oo < 32; ++oo) {
    int o = (oo << 2) + sl;
    float f0 = 0.f, f1 = 0.f, f2 = 0.f, f3 = 0.f;
    #pragma unroll
    for (int j = 0; j < 16; ++j) {
      float4 w = w2s[o*17 + j];
      f0 = fmaf(w.x, hreg[4*j+0], f0);
      f1 = fmaf(w.y, hreg[4*j+1], f1);
      f2 = fmaf(w.z, hreg[4*j+2], f2);
      f3 = fmaf(w.w, hreg[4*j+3], f3);
    }
    float f = (f0+f1)+(f2+f3);
    #pragma unroll
    for (int j = 0; j < 4; ++j) {
      float4 wq_ = wts[o*9 + j];
      qa[4*j+0] = fmaf(wq_.x, f, qa[4*j+0]);
      qa[4*j+1] = fmaf(wq_.y, f, qa[4*j+1]);
      qa[4*j+2] = fmaf(wq_.z, f, qa[4*j+2]);
      qa[4*j+3] = fmaf(wq_.w, f, qa[4*j+3]);
      float4 wk_ = wts[o*9 + 4 + j];
      ka[4*j+0] = fmaf(wk_.x, f, ka[4*j+0]);
      ka[4*j+1] = fmaf(wk_.y, f, ka[4*j+1]);
      ka[4*j+2] = fmaf(wk_.z, f, ka[4*j+2]);
      ka[4*j+3] = fmaf(wk_.w, f, ka[4*j+3]);
    }
    float4 wv_ = wts[o*9 + 8];
    va0 = fmaf(wv_.x, f, va0); va1 = fmaf(wv_.y, f, va1); va2 = fmaf(wv_.z, f, va2);
  }
  // combine the 4 o-slices (lanes xor 16, 32)
  #pragma unroll
  for (int off = 16; off <= 32; off <<= 1) {
    #pragma unroll
    for (int d2 = 0; d2 < 16; ++d2) {
      qa[d2] += __shfl_xor(qa[d2], off);
      ka[d2] += __shfl_xor(ka[d2], off);
    }
    va0 += __shfl_xor(va0, off); va1 += __shfl_xor(va1, off); va2 += __shfl_xor(va2, off);
  }
  if (sl == 0) {
    #pragma unroll
    for (int d2 = 0; d2 < 16; ++d2) {
      qp[(size_t)(b*16+d2)*NN + n] = qa[d2];
      kp[(size_t)(b*16+d2)*NN + n] = ka[d2];
    }
    vp[(size_t)(b*3+0)*NN + n] = va0;
    vp[(size_t)(b*3+1)*NN + n] = va1;
    vp[(size_t)(b*3+2)*NN + n] = va2;
  }
  // stats: each 16-lane group holds full values for its 16 points (x4 dup);
  // reduce within group, one atomic per wave.
  bool lead = (l == 0);
  #pragma unroll
  for (int d2 = 0; d2 < 16; ++d2) {
    float s = qa[d2], q = qa[d2]*qa[d2];
    red16_2(s, q);
    if (lead) { atomicAdd(&st[128+d2], s); atomicAdd(&st[144+d2], q); }
    s = ka[d2]; q = ka[d2]*ka[d2];
    red16_2(s, q);
    if (lead) { atomicAdd(&st[160+d2], s); atomicAdd(&st[176+d2], q); }
  }
  float s = va0, q = va0*va0; red16_2(s, q);
  if (lead) { atomicAdd(&st[192], s); atomicAdd(&st[195], q); }
  s = va1; q = va1*va1; red16_2(s, q);
  if (lead) { atomicAdd(&st[193], s); atomicAdd(&st[196], q); }
  s = va2; q = va2*va2; red16_2(s, q);
  if (lead) { atomicAdd(&st[194], s); atomicAdd(&st[197], q); }
}

// ---- F2: finalize BN2/3/4 --------------------------------------------------
__global__ void f2_fin(const float* __restrict__ st,
                       const float* __restrict__ g2, const float* __restrict__ b2,
                       const float* __restrict__ g3, const float* __restrict__ b3,
                       const float* __restrict__ g4, const float* __restrict__ b4,
                       float* __restrict__ pr) {
  int i = threadIdx.x;
  if (i < 16) {
    float mean = st[128+i] * INV_CNT;
    float var  = st[144+i] * INV_CNT - mean*mean;
    float sc = g2[i] * rsqrtf(var + EPS);
    pr[128+i] = sc; pr[144+i] = fmaf(-mean, sc, b2[i]);
  } else if (i < 32) {
    int d = i - 16;
    float mean = st[160+d] * INV_CNT;
    float var  = st[176+d] * INV_CNT - mean*mean;
    float sc = g3[d] * rsqrtf(var + EPS);
    pr[160+d] = sc; pr[176+d] = fmaf(-mean, sc, b3[d]);
  } else if (i < 35) {
    int d = i - 32;
    float mean = st[192+d] * INV_CNT;
    float var  = st[195+d] * INV_CNT - mean*mean;
    float sc = g4[d] * rsqrtf(var + EPS);
    pr[192+d] = sc; pr[195+d] = fmaf(-mean, sc, b4[d]);
  }
}

// ---- K5: flash attention, [mm][20]-transposed q||v in LDS ------------------
__global__ __launch_bounds__(256) void k5_attn(
    const float* __restrict__ qp, const float* __restrict__ kp,
    const float* __restrict__ vp, const float* __restrict__ pr,
    const float* __restrict__ x, const float* __restrict__ alpha,
    float* __restrict__ out) {
  __shared__ float4 qvs[128*5];          // [mm][20 floats]: q0..15, v0..2, pad
  __shared__ float spr[70];
  float* qv = (float*)qvs;
  int tx = threadIdx.x;
  if (tx < 70) spr[tx] = pr[128 + tx];
  int b = blockIdx.x >> 6;
  int row = ((blockIdx.x & 63) << 6) + (tx >> 2);
  int p = tx & 3;
  __syncthreads();
  float kv[16];
  #pragma unroll
  for (int d = 0; d < 16; ++d) {
    float t = fmaf(kp[(size_t)(b*16+d)*NN + row], spr[32+d], spr[48+d]);
    kv[d] = fmaxf(t, 0.f);
  }
  float mcur = 0.f, lsum = 0.f, a0 = 0.f, a1 = 0.f, a2 = 0.f;  // scores >= 0
  for (int m0 = 0; m0 < NN; m0 += 128) {
    __syncthreads();
    for (int i = tx; i < 2048; i += 256) {
      int d = i >> 7, mm = i & 127;
      float t = fmaf(qp[(size_t)(b*16+d)*NN + m0 + mm], spr[d], spr[16+d]);
      qv[mm*20 + d] = fmaxf(t, 0.f);
    }
    for (int i = tx; i < 384; i += 256) {
      int d = i >> 7, mm = i & 127;
      float t = fmaf(vp[(size_t)(b*3+d)*NN + m0 + mm], spr[64+d], spr[67+d]);
      qv[mm*20 + 16 + d] = fmaxf(t, 0.f);
    }
    __syncthreads();
    const float4* qv4 = (const float4*)qv;
    for (int mm = p; mm < 128; mm += 4) {
      float4 q0 = qv4[mm*5+0], q1 = qv4[mm*5+1], q2 = qv4[mm*5+2], q3 = qv4[mm*5+3];
      float4 vv = qv4[mm*5+4];
      float s0 = kv[0]*q0.x, s1 = kv[1]*q0.y, s2 = kv[2]*q0.z, s3 = kv[3]*q0.w;
      s0 = fmaf(kv[4],  q1.x, s0); s1 = fmaf(kv[5],  q1.y, s1);
      s2 = fmaf(kv[6],  q1.z, s2); s3 = fmaf(kv[7],  q1.w, s3);
      s0 = fmaf(kv[8],  q2.x, s0); s1 = fmaf(kv[9],  q2.y, s1);
      s2 = fmaf(kv[10], q2.z, s2); s3 = fmaf(kv[11], q2.w, s3);
      s0 = fmaf(kv[12], q3.x, s0); s1 = fmaf(kv[13], q3.y, s1);
      s2 = fmaf(kv[14], q3.z, s2); s3 = fmaf(kv[15], q3.w, s3);
      float s = (s0+s1)+(s2+s3);
      float pw = __expf(s - mcur);
      if (s - mcur > 8.f) {               // rare rescale (defer-max, THR=8)
        float c = __expf(mcur - s);
        lsum *= c; a0 *= c; a1 *= c; a2 *= c; mcur = s; pw = 1.f;
      }
      lsum += pw;
      a0 = fmaf(pw, vv.x, a0);
      a1 = fmaf(pw, vv.y, a1);
      a2 = fmaf(pw, vv.z, a2);
    }
  }
  #pragma unroll
  for (int off = 1; off <= 2; off <<= 1) {
    float om = __shfl_xor(mcur, off), ol = __shfl_xor(lsum, off);
    float o0 = __shfl_xor(a0, off), o1 = __shfl_xor(a1, off), o2 = __shfl_xor(a2, off);
    float mn = fmaxf(mcur, om);
    float c1 = __expf(mcur - mn), c2 = __expf(om - mn);
    lsum = lsum*c1 + ol*c2;
    a0 = a0*c1 + o0*c2; a1 = a1*c1 + o1*c2; a2 = a2*c1 + o2*c2;
    mcur = mn;
  }
  if (p == 0) {
    float inv = 1.f / lsum, al = alpha[0];
    out[(size_t)(b*3+0)*NN + row] = fmaf(al, a0*inv, x[(size_t)(b*3+0)*NN + row]);
    out[(size_t)(b*3+1)*NN + row] = fmaf(al, a1*inv, x[(size_t)(b*3+1)*NN + row]);
    out[(size_t)(b*3+2)*NN + row] = fmaf(al, a2*inv, x[(size_t)(b*3+2)*NN + row]);
  }
}

extern "C" void kernel_launch(void* const* d_in, const int* in_sizes, int n_in,
                              void* d_out, int out_size, void* d_ws, size_t ws_size,
                              hipStream_t stream) {
  const float* x    = (const float*)d_in[0];
  const float* w1   = (const float*)d_in[1];
  const float* g1   = (const float*)d_in[2];
  const float* b1   = (const float*)d_in[3];
  const float* w2   = (const float*)d_in[4];
  const float* wq   = (const float*)d_in[5];
  const float* g2   = (const float*)d_in[6];
  const float* b2   = (const float*)d_in[7];
  const float* wk   = (const float*)d_in[8];
  const float* g3   = (const float*)d_in[9];
  const float* b3   = (const float*)d_in[10];
  const float* wv   = (const float*)d_in[11];
  const float* g4   = (const float*)d_in[12];
  const float* b4   = (const float*)d_in[13];
  const float* alpha= (const float*)d_in[14];
  float* out = (float*)d_out;
  float* ws  = (float*)d_ws;

  float* qpre = ws + OFF_QP;
  float* kpre = ws + OFF_KP;
  float* vpre = ws + OFF_VP;
  float* st   = ws + OFF_ST;
  float* pr   = ws + OFF_PR;
  float* w1p  = ws + OFF_W1P;

  hipMemsetAsync(st, 0, 256*sizeof(float), stream);
  k0_xmom<<<128, 256, 0, stream>>>(x, st);
  f1_fin<<<1, 64, 0, stream>>>(st, w1, g1, b1, w1p);
  k3_feat_qkv<<<512, 256, 0, stream>>>(x, w2, wq, wk, wv, w1p, qpre, kpre, vpre, st);
  f2_fin<<<1, 64, 0, stream>>>(st, g2, b2, g3, b3, g4, b4, pr);
  k5_attn<<<512, 256, 0, stream>>>(qpre, kpre, vpre, pr, x, alpha, out);
}

// Round 3
// 483.818 us; speedup vs baseline: 2.3236x; 2.3236x over previous
//
#include <hip/hip_runtime.h>

#define EPS 1e-5f
constexpr int NN = 4096;
constexpr float INV_CNT = 1.0f / (8.0f * 4096.0f);

// workspace layout (float offsets)
constexpr size_t OFF_QP  = 0;        // 524288
constexpr size_t OFF_KP  = 524288;   // 524288
constexpr size_t OFF_VP  = 1048576;  // 98304
constexpr size_t OFF_ST  = 1146880;  // 256 stats
constexpr size_t OFF_PR  = 1147136;  // 256 BN2/3/4 scale/shift
constexpr size_t OFF_W1P = 1147392;  // 256 folded w1
constexpr size_t OFF_WT2 = 1147648;  // 64*36 = 2304 combined Wq2/Wk2/Wv2, c-major
constexpr size_t OFF_PM  = 1149952;  // 8*32768 partial m
constexpr size_t OFF_PL  = 1412096;  // partial l
constexpr size_t OFF_PA0 = 1674240;
constexpr size_t OFF_PA1 = 1936384;
constexpr size_t OFF_PA2 = 2198528;  // total 2460672 floats = 9.85 MB

// ---- K0: x first/second moments (9 scalars) --------------------------------
__global__ __launch_bounds__(256) void k0_xmom(const float* __restrict__ x,
                                               float* __restrict__ st) {
  int idx = blockIdx.x * 256 + threadIdx.x;
  int b = idx >> 12, n = idx & 4095;
  float x0 = x[(size_t)(b*3+0)*NN + n];
  float x1 = x[(size_t)(b*3+1)*NN + n];
  float x2 = x[(size_t)(b*3+2)*NN + n];
  float m[9] = {x0, x1, x2, x0*x0, x0*x1, x0*x2, x1*x1, x1*x2, x2*x2};
  #pragma unroll
  for (int off = 32; off; off >>= 1) {
    #pragma unroll
    for (int j = 0; j < 9; ++j) m[j] += __shfl_xor(m[j], off);
  }
  if ((threadIdx.x & 63) == 0) {
    #pragma unroll
    for (int j = 0; j < 9; ++j) atomicAdd(&st[j], m[j]);
  }
}

// ---- F0: combined weights Wq2 = wq@w2 etc., stored c-major [c][36] ---------
__global__ __launch_bounds__(256) void f0_wcomb(const float* __restrict__ w2,
                                                const float* __restrict__ wq,
                                                const float* __restrict__ wk,
                                                const float* __restrict__ wv,
                                                float* __restrict__ wt2) {
  __shared__ float w2s[8192];     // [o][c]
  __shared__ float wr[4480];      // rows: j<16 wq, 16<=j<32 wk, 32<=j<35 wv
  int tx = threadIdx.x;
  for (int i = tx; i < 8192; i += 256) w2s[i] = w2[i];
  for (int i = tx; i < 2048; i += 256) { wr[i] = wq[i]; wr[2048+i] = wk[i]; }
  for (int i = tx; i < 384; i += 256) wr[4096+i] = wv[i];
  __syncthreads();
  for (int e = tx; e < 2240; e += 256) {
    int j = e >> 6, c = e & 63;
    float s = 0.f;
    #pragma unroll 4
    for (int o = 0; o < 128; ++o) s = fmaf(wr[j*128+o], w2s[o*64+c], s);
    wt2[c*36 + j] = s;
  }
}

// ---- F1: analytic BN1 params folded into w1 --------------------------------
__global__ void f1_fin(const float* __restrict__ st, const float* __restrict__ w1,
                       const float* __restrict__ g1, const float* __restrict__ b1,
                       float* __restrict__ w1p) {
  int c = threadIdx.x;  // 64
  float mx0 = st[0]*INV_CNT, mx1 = st[1]*INV_CNT, mx2 = st[2]*INV_CNT;
  float M00 = st[3]*INV_CNT, M01 = st[4]*INV_CNT, M02 = st[5]*INV_CNT;
  float M11 = st[6]*INV_CNT, M12 = st[7]*INV_CNT, M22 = st[8]*INV_CNT;
  float a = w1[c*3], b_ = w1[c*3+1], d = w1[c*3+2];
  float mean = a*mx0 + b_*mx1 + d*mx2;
  float e2 = a*a*M00 + b_*b_*M11 + d*d*M22 + 2.f*(a*b_*M01 + a*d*M02 + b_*d*M12);
  float sc = g1[c] * rsqrtf(e2 - mean*mean + EPS);
  w1p[c*4+0] = a*sc; w1p[c*4+1] = b_*sc; w1p[c*4+2] = d*sc;
  w1p[c*4+3] = fmaf(-mean, sc, b1[c]);
}

// ---- K3: per point, stream channels -> qa/ka/va (no feat, no hreg array) ---
__global__ __launch_bounds__(256, 2) void k3_qkv(
    const float* __restrict__ x, const float* __restrict__ w1p,
    const float* __restrict__ wt2,
    float* __restrict__ qp, float* __restrict__ kp, float* __restrict__ vp,
    float* __restrict__ st) {
  __shared__ float4 w1s[64];
  __shared__ float4 wt2s[576];   // [c][9 float4]: q0..15, k0..15, v0..2+pad
  int tx = threadIdx.x;
  for (int i = tx; i < 576; i += 256) wt2s[i] = ((const float4*)wt2)[i];
  if (tx < 64) w1s[tx] = ((const float4*)w1p)[tx];
  __syncthreads();
  int idx = blockIdx.x*256 + tx;
  int b = idx >> 12, n = idx & 4095;
  float x0 = x[(size_t)(b*3+0)*NN + n];
  float x1 = x[(size_t)(b*3+1)*NN + n];
  float x2 = x[(size_t)(b*3+2)*NN + n];
  float qa[16] = {}, ka[16] = {};
  float va0 = 0.f, va1 = 0.f, va2 = 0.f;
  #pragma unroll 4
  for (int c = 0; c < 64; ++c) {
    float4 w = w1s[c];
    float h = fmaf(w.x, x0, fmaf(w.y, x1, fmaf(w.z, x2, w.w)));
    h = h > 0.f ? h : 0.2f*h;
    #pragma unroll
    for (int j = 0; j < 4; ++j) {
      float4 A = wt2s[c*9 + j];
      qa[4*j+0] = fmaf(A.x, h, qa[4*j+0]);
      qa[4*j+1] = fmaf(A.y, h, qa[4*j+1]);
      qa[4*j+2] = fmaf(A.z, h, qa[4*j+2]);
      qa[4*j+3] = fmaf(A.w, h, qa[4*j+3]);
      float4 B = wt2s[c*9 + 4 + j];
      ka[4*j+0] = fmaf(B.x, h, ka[4*j+0]);
      ka[4*j+1] = fmaf(B.y, h, ka[4*j+1]);
      ka[4*j+2] = fmaf(B.z, h, ka[4*j+2]);
      ka[4*j+3] = fmaf(B.w, h, ka[4*j+3]);
    }
    float4 V = wt2s[c*9 + 8];
    va0 = fmaf(V.x, h, va0); va1 = fmaf(V.y, h, va1); va2 = fmaf(V.z, h, va2);
  }
  #pragma unroll
  for (int d = 0; d < 16; ++d) {
    qp[(size_t)(b*16+d)*NN + n] = qa[d];
    kp[(size_t)(b*16+d)*NN + n] = ka[d];
  }
  vp[(size_t)(b*3+0)*NN + n] = va0;
  vp[(size_t)(b*3+1)*NN + n] = va1;
  vp[(size_t)(b*3+2)*NN + n] = va2;
  // stats: wave butterfly, lane0 atomics
  bool lead = ((tx & 63) == 0);
  #pragma unroll
  for (int d = 0; d < 16; ++d) {
    float s = qa[d], q = qa[d]*qa[d];
    #pragma unroll
    for (int off = 32; off; off >>= 1) { s += __shfl_xor(s, off); q += __shfl_xor(q, off); }
    if (lead) { atomicAdd(&st[128+d], s); atomicAdd(&st[144+d], q); }
    s = ka[d]; q = ka[d]*ka[d];
    #pragma unroll
    for (int off = 32; off; off >>= 1) { s += __shfl_xor(s, off); q += __shfl_xor(q, off); }
    if (lead) { atomicAdd(&st[160+d], s); atomicAdd(&st[176+d], q); }
  }
  float vv[3] = {va0, va1, va2};
  #pragma unroll
  for (int d = 0; d < 3; ++d) {
    float s = vv[d], q = vv[d]*vv[d];
    #pragma unroll
    for (int off = 32; off; off >>= 1) { s += __shfl_xor(s, off); q += __shfl_xor(q, off); }
    if (lead) { atomicAdd(&st[192+d], s); atomicAdd(&st[195+d], q); }
  }
}

// ---- F2: finalize BN2/3/4 --------------------------------------------------
__global__ void f2_fin(const float* __restrict__ st,
                       const float* __restrict__ g2, const float* __restrict__ b2,
                       const float* __restrict__ g3, const float* __restrict__ b3,
                       const float* __restrict__ g4, const float* __restrict__ b4,
                       float* __restrict__ pr) {
  int i = threadIdx.x;
  if (i < 16) {
    float mean = st[128+i]*INV_CNT, var = st[144+i]*INV_CNT - mean*mean;
    float sc = g2[i]*rsqrtf(var + EPS);
    pr[128+i] = sc; pr[144+i] = fmaf(-mean, sc, b2[i]);
  } else if (i < 32) {
    int d = i-16;
    float mean = st[160+d]*INV_CNT, var = st[176+d]*INV_CNT - mean*mean;
    float sc = g3[d]*rsqrtf(var + EPS);
    pr[160+d] = sc; pr[176+d] = fmaf(-mean, sc, b3[d]);
  } else if (i < 35) {
    int d = i-32;
    float mean = st[192+d]*INV_CNT, var = st[195+d]*INV_CNT - mean*mean;
    float sc = g4[d]*rsqrtf(var + EPS);
    pr[192+d] = sc; pr[195+d] = fmaf(-mean, sc, b4[d]);
  }
}

// ---- K5: flash attention, 4 rows/thread, 8-way column split ----------------
// block: b = blk>>5, rowchunk rc = (blk>>3)&3, colchunk cb = blk&7
__global__ __launch_bounds__(256, 2) void k5_attn(
    const float* __restrict__ qp, const float* __restrict__ kp,
    const float* __restrict__ vp, const float* __restrict__ pr,
    float* __restrict__ pm, float* __restrict__ pl,
    float* __restrict__ pa0, float* __restrict__ pa1, float* __restrict__ pa2) {
  __shared__ float4 qvs[128*5];    // [mm][20 floats]: q0..15, v0..2, pad
  __shared__ float spr[70];
  float* qv = (float*)qvs;
  int tx = threadIdx.x;
  if (tx < 70) spr[tx] = pr[128 + tx];
  int b  = blockIdx.x >> 5;
  int rc = (blockIdx.x >> 3) & 3;
  int cb = blockIdx.x & 7;
  int n0 = rc*1024 + tx;           // rows n0 + 256*r
  __syncthreads();
  float kv[64];
  #pragma unroll
  for (int r = 0; r < 4; ++r)
    #pragma unroll
    for (int d = 0; d < 16; ++d) {
      float t = fmaf(kp[(size_t)(b*16+d)*NN + n0 + r*256], spr[32+d], spr[48+d]);
      kv[r*16+d] = fmaxf(t, 0.f);
    }
  float m[4] = {0,0,0,0}, l[4] = {0,0,0,0};
  float a0[4] = {0,0,0,0}, a1[4] = {0,0,0,0}, a2[4] = {0,0,0,0};
  int c0 = cb << 9;
  for (int m0 = c0; m0 < c0 + 512; m0 += 128) {
    __syncthreads();
    for (int i = tx; i < 2048; i += 256) {
      int d = i >> 7, mm = i & 127;
      float t = fmaf(qp[(size_t)(b*16+d)*NN + m0 + mm], spr[d], spr[16+d]);
      qv[mm*20 + d] = fmaxf(t, 0.f);
    }
    for (int i = tx; i < 384; i += 256) {
      int d = i >> 7, mm = i & 127;
      float t = fmaf(vp[(size_t)(b*3+d)*NN + m0 + mm], spr[64+d], spr[67+d]);
      qv[mm*20 + 16 + d] = fmaxf(t, 0.f);
    }
    __syncthreads();
    const float4* qv4 = (const float4*)qv;
    #pragma unroll 2
    for (int mm = 0; mm < 128; ++mm) {
      float4 q0 = qv4[mm*5+0], q1 = qv4[mm*5+1], q2 = qv4[mm*5+2], q3 = qv4[mm*5+3];
      float4 vvv = qv4[mm*5+4];
      #pragma unroll
      for (int r = 0; r < 4; ++r) {
        float t0 = kv[r*16+0]*q0.x, t1 = kv[r*16+1]*q0.y;
        float t2 = kv[r*16+2]*q0.z, t3 = kv[r*16+3]*q0.w;
        t0 = fmaf(kv[r*16+4],  q1.x, t0); t1 = fmaf(kv[r*16+5],  q1.y, t1);
        t2 = fmaf(kv[r*16+6],  q1.z, t2); t3 = fmaf(kv[r*16+7],  q1.w, t3);
        t0 = fmaf(kv[r*16+8],  q2.x, t0); t1 = fmaf(kv[r*16+9],  q2.y, t1);
        t2 = fmaf(kv[r*16+10], q2.z, t2); t3 = fmaf(kv[r*16+11], q2.w, t3);
        t0 = fmaf(kv[r*16+12], q3.x, t0); t1 = fmaf(kv[r*16+13], q3.y, t1);
        t2 = fmaf(kv[r*16+14], q3.z, t2); t3 = fmaf(kv[r*16+15], q3.w, t3);
        float s = (t0+t1)+(t2+t3);
        float pw = __expf(s - m[r]);
        if (s - m[r] > 8.f) {            // rare rescale (defer-max, THR=8)
          float cc = __expf(m[r] - s);
          l[r] *= cc; a0[r] *= cc; a1[r] *= cc; a2[r] *= cc; m[r] = s; pw = 1.f;
        }
        l[r] += pw;
        a0[r] = fmaf(pw, vvv.x, a0[r]);
        a1[r] = fmaf(pw, vvv.y, a1[r]);
        a2[r] = fmaf(pw, vvv.z, a2[r]);
      }
    }
  }
  #pragma unroll
  for (int r = 0; r < 4; ++r) {
    size_t row = (size_t)cb*32768 + b*4096 + n0 + r*256;
    pm[row] = m[r]; pl[row] = l[r];
    pa0[row] = a0[r]; pa1[row] = a1[r]; pa2[row] = a2[r];
  }
}

// ---- K6: merge 8 column-chunk partials + epilogue --------------------------
__global__ __launch_bounds__(256) void k6_merge(
    const float* __restrict__ pm, const float* __restrict__ pl,
    const float* __restrict__ pa0, const float* __restrict__ pa1,
    const float* __restrict__ pa2, const float* __restrict__ x,
    const float* __restrict__ alpha, float* __restrict__ out) {
  int row = blockIdx.x*256 + threadIdx.x;   // 0..32767
  float M = 0.f, L = 0.f, A0 = 0.f, A1 = 0.f, A2 = 0.f;
  #pragma unroll
  for (int cb = 0; cb < 8; ++cb) {
    size_t i = (size_t)cb*32768 + row;
    float pmv = pm[i];
    float mn = fmaxf(M, pmv);
    float c1 = __expf(M - mn), c2 = __expf(pmv - mn);
    L  = L*c1  + pl[i]*c2;
    A0 = A0*c1 + pa0[i]*c2;
    A1 = A1*c1 + pa1[i]*c2;
    A2 = A2*c1 + pa2[i]*c2;
    M = mn;
  }
  int b = row >> 12, n = row & 4095;
  float inv = 1.f / L, al = alpha[0];
  out[(size_t)(b*3+0)*NN + n] = fmaf(al, A0*inv, x[(size_t)(b*3+0)*NN + n]);
  out[(size_t)(b*3+1)*NN + n] = fmaf(al, A1*inv, x[(size_t)(b*3+1)*NN + n]);
  out[(size_t)(b*3+2)*NN + n] = fmaf(al, A2*inv, x[(size_t)(b*3+2)*NN + n]);
}

extern "C" void kernel_launch(void* const* d_in, const int* in_sizes, int n_in,
                              void* d_out, int out_size, void* d_ws, size_t ws_size,
                              hipStream_t stream) {
  const float* x    = (const float*)d_in[0];
  const float* w1   = (const float*)d_in[1];
  const float* g1   = (const float*)d_in[2];
  const float* b1   = (const float*)d_in[3];
  const float* w2   = (const float*)d_in[4];
  const float* wq   = (const float*)d_in[5];
  const float* g2   = (const float*)d_in[6];
  const float* b2   = (const float*)d_in[7];
  const float* wk   = (const float*)d_in[8];
  const float* g3   = (const float*)d_in[9];
  const float* b3   = (const float*)d_in[10];
  const float* wv   = (const float*)d_in[11];
  const float* g4   = (const float*)d_in[12];
  const float* b4   = (const float*)d_in[13];
  const float* alpha= (const float*)d_in[14];
  float* out = (float*)d_out;
  float* ws  = (float*)d_ws;

  float* qpre = ws + OFF_QP;
  float* kpre = ws + OFF_KP;
  float* vpre = ws + OFF_VP;
  float* st   = ws + OFF_ST;
  float* pr   = ws + OFF_PR;
  float* w1p  = ws + OFF_W1P;
  float* wt2  = ws + OFF_WT2;
  float* pm   = ws + OFF_PM;
  float* pl   = ws + OFF_PL;
  float* pa0  = ws + OFF_PA0;
  float* pa1  = ws + OFF_PA1;
  float* pa2  = ws + OFF_PA2;

  hipMemsetAsync(st, 0, 256*sizeof(float), stream);
  k0_xmom<<<128, 256, 0, stream>>>(x, st);
  f0_wcomb<<<1, 256, 0, stream>>>(w2, wq, wk, wv, wt2);
  f1_fin<<<1, 64, 0, stream>>>(st, w1, g1, b1, w1p);
  k3_qkv<<<128, 256, 0, stream>>>(x, w1p, wt2, qpre, kpre, vpre, st);
  f2_fin<<<1, 64, 0, stream>>>(st, g2, b2, g3, b3, g4, b4, pr);
  k5_attn<<<256, 256, 0, stream>>>(qpre, kpre, vpre, pr, pm, pl, pa0, pa1, pa2);
  k6_merge<<<128, 256, 0, stream>>>(pm, pl, pa0, pa1, pa2, x, alpha, out);
}

// Round 4
// 173.896 us; speedup vs baseline: 6.4647x; 2.7822x over previous
//
#include <hip/hip_runtime.h>

#define EPS 1e-5f
constexpr int NN = 4096;
constexpr float INV_CNT = 1.0f / (8.0f * 4096.0f);

// workspace layout (float offsets)
constexpr size_t OFF_QP  = 0;        // 524288
constexpr size_t OFF_KP  = 524288;   // 524288
constexpr size_t OFF_VP  = 1048576;  // 98304
constexpr size_t OFF_PR  = 1146880;  // 256  BN2/3/4 scale/shift
constexpr size_t OFF_W1P = 1147136;  // 256  folded w1
constexpr size_t OFF_WT2 = 1147392;  // 2304 combined Wq2/Wk2/Wv2, c-major
constexpr size_t OFF_XP  = 1149696;  // 9*128 x-moment block partials [j][blk]
constexpr size_t OFF_BS  = 1150848;  // 70*128 qkv-stat block partials [s][blk]
constexpr size_t OFF_PM  = 1159808;  // 16*32768 partial m
constexpr size_t OFF_PL  = 1684096;
constexpr size_t OFF_PA0 = 2208384;
constexpr size_t OFF_PA1 = 2732672;
constexpr size_t OFF_PA2 = 3256960;  // end 3781248 floats = 14.4 MiB

// ---- K0: x moments -> block partials (no atomics) --------------------------
__global__ __launch_bounds__(256) void k0_xmom(const float* __restrict__ x,
                                               float* __restrict__ xpart) {
  __shared__ float sred[36];
  int tx = threadIdx.x;
  int idx = blockIdx.x * 256 + tx;
  int b = idx >> 12, n = idx & 4095;
  float x0 = x[(size_t)(b*3+0)*NN + n];
  float x1 = x[(size_t)(b*3+1)*NN + n];
  float x2 = x[(size_t)(b*3+2)*NN + n];
  float m[9] = {x0, x1, x2, x0*x0, x0*x1, x0*x2, x1*x1, x1*x2, x2*x2};
  #pragma unroll
  for (int off = 32; off; off >>= 1) {
    #pragma unroll
    for (int j = 0; j < 9; ++j) m[j] += __shfl_xor(m[j], off);
  }
  int w = tx >> 6;
  if ((tx & 63) == 0) {
    #pragma unroll
    for (int j = 0; j < 9; ++j) sred[w*9+j] = m[j];
  }
  __syncthreads();
  if (tx < 9) xpart[tx*128 + blockIdx.x] = sred[tx] + sred[9+tx] + sred[18+tx] + sred[27+tx];
}

// ---- F0: combined weights Wq2 = wq@w2 etc., stored c-major [c][36] ---------
__global__ __launch_bounds__(256) void f0_wcomb(const float* __restrict__ w2,
                                                const float* __restrict__ wq,
                                                const float* __restrict__ wk,
                                                const float* __restrict__ wv,
                                                float* __restrict__ wt2) {
  __shared__ float w2s[8192];     // [o][c]
  __shared__ float wr[4480];      // rows: j<16 wq, 16<=j<32 wk, 32<=j<35 wv
  int tx = threadIdx.x;
  for (int i = tx; i < 8192; i += 256) w2s[i] = w2[i];
  for (int i = tx; i < 2048; i += 256) { wr[i] = wq[i]; wr[2048+i] = wk[i]; }
  for (int i = tx; i < 384; i += 256) wr[4096+i] = wv[i];
  __syncthreads();
  for (int e = tx; e < 2240; e += 256) {
    int j = e >> 6, c = e & 63;
    float s = 0.f;
    #pragma unroll 4
    for (int o = 0; o < 128; ++o) s = fmaf(wr[j*128+o], w2s[o*64+c], s);
    wt2[c*36 + j] = s;
  }
}

// ---- F1: reduce x-moment partials, fold BN1 into w1 ------------------------
__global__ void f1_fin(const float* __restrict__ xpart, const float* __restrict__ w1,
                       const float* __restrict__ g1, const float* __restrict__ b1,
                       float* __restrict__ w1p) {
  __shared__ float mom[9];
  int tx = threadIdx.x;   // 64
  if (tx < 9) {
    float acc = 0.f;
    #pragma unroll 8
    for (int i = 0; i < 128; ++i) acc += xpart[tx*128 + i];
    mom[tx] = acc * INV_CNT;
  }
  __syncthreads();
  int c = tx;
  float a = w1[c*3], b_ = w1[c*3+1], d = w1[c*3+2];
  float mean = a*mom[0] + b_*mom[1] + d*mom[2];
  float e2 = a*a*mom[3] + b_*b_*mom[6] + d*d*mom[8]
           + 2.f*(a*b_*mom[4] + a*d*mom[5] + b_*d*mom[7]);
  float sc = g1[c] * rsqrtf(e2 - mean*mean + EPS);
  w1p[c*4+0] = a*sc; w1p[c*4+1] = b_*sc; w1p[c*4+2] = d*sc;
  w1p[c*4+3] = fmaf(-mean, sc, b1[c]);
}

// ---- K3: per point -> qa/ka/va + block-partial stats (no atomics) ----------
__global__ __launch_bounds__(256, 2) void k3_qkv(
    const float* __restrict__ x, const float* __restrict__ w1p,
    const float* __restrict__ wt2,
    float* __restrict__ qp, float* __restrict__ kp, float* __restrict__ vp,
    float* __restrict__ bs) {
  __shared__ float4 w1s[64];
  __shared__ float4 wt2s[576];   // [c][9 float4]: q0..15, k0..15, v0..2+pad
  __shared__ float sred[280];    // [w][70]
  int tx = threadIdx.x;
  for (int i = tx; i < 576; i += 256) wt2s[i] = ((const float4*)wt2)[i];
  if (tx < 64) w1s[tx] = ((const float4*)w1p)[tx];
  __syncthreads();
  int idx = blockIdx.x*256 + tx;
  int b = idx >> 12, n = idx & 4095;
  float x0 = x[(size_t)(b*3+0)*NN + n];
  float x1 = x[(size_t)(b*3+1)*NN + n];
  float x2 = x[(size_t)(b*3+2)*NN + n];
  float qa[16] = {}, ka[16] = {};
  float va0 = 0.f, va1 = 0.f, va2 = 0.f;
  #pragma unroll 4
  for (int c = 0; c < 64; ++c) {
    float4 w = w1s[c];
    float h = fmaf(w.x, x0, fmaf(w.y, x1, fmaf(w.z, x2, w.w)));
    h = h > 0.f ? h : 0.2f*h;
    #pragma unroll
    for (int j = 0; j < 4; ++j) {
      float4 A = wt2s[c*9 + j];
      qa[4*j+0] = fmaf(A.x, h, qa[4*j+0]);
      qa[4*j+1] = fmaf(A.y, h, qa[4*j+1]);
      qa[4*j+2] = fmaf(A.z, h, qa[4*j+2]);
      qa[4*j+3] = fmaf(A.w, h, qa[4*j+3]);
      float4 B = wt2s[c*9 + 4 + j];
      ka[4*j+0] = fmaf(B.x, h, ka[4*j+0]);
      ka[4*j+1] = fmaf(B.y, h, ka[4*j+1]);
      ka[4*j+2] = fmaf(B.z, h, ka[4*j+2]);
      ka[4*j+3] = fmaf(B.w, h, ka[4*j+3]);
    }
    float4 V = wt2s[c*9 + 8];
    va0 = fmaf(V.x, h, va0); va1 = fmaf(V.y, h, va1); va2 = fmaf(V.z, h, va2);
  }
  #pragma unroll
  for (int d = 0; d < 16; ++d) {
    qp[(size_t)(b*16+d)*NN + n] = qa[d];
    kp[(size_t)(b*16+d)*NN + n] = ka[d];
  }
  vp[(size_t)(b*3+0)*NN + n] = va0;
  vp[(size_t)(b*3+1)*NN + n] = va1;
  vp[(size_t)(b*3+2)*NN + n] = va2;
  // stats: wave butterfly -> LDS -> one plain store per stat per block
  int w = tx >> 6;
  bool lead = ((tx & 63) == 0);
  #pragma unroll
  for (int d = 0; d < 16; ++d) {
    float s = qa[d], q = qa[d]*qa[d];
    #pragma unroll
    for (int off = 32; off; off >>= 1) { s += __shfl_xor(s, off); q += __shfl_xor(q, off); }
    if (lead) { sred[w*70 + d] = s; sred[w*70 + 16 + d] = q; }
    s = ka[d]; q = ka[d]*ka[d];
    #pragma unroll
    for (int off = 32; off; off >>= 1) { s += __shfl_xor(s, off); q += __shfl_xor(q, off); }
    if (lead) { sred[w*70 + 32 + d] = s; sred[w*70 + 48 + d] = q; }
  }
  float vv[3] = {va0, va1, va2};
  #pragma unroll
  for (int d = 0; d < 3; ++d) {
    float s = vv[d], q = vv[d]*vv[d];
    #pragma unroll
    for (int off = 32; off; off >>= 1) { s += __shfl_xor(s, off); q += __shfl_xor(q, off); }
    if (lead) { sred[w*70 + 64 + d] = s; sred[w*70 + 67 + d] = q; }
  }
  __syncthreads();
  if (tx < 70)
    bs[tx*128 + blockIdx.x] = sred[tx] + sred[70+tx] + sred[140+tx] + sred[210+tx];
}

// ---- F2: reduce stat partials, finalize BN2/3/4 ----------------------------
// tot layout: 0..15 qsum, 16..31 qssq, 32..47 ksum, 48..63 kssq, 64..66 vsum, 67..69 vssq
__global__ void f2_fin(const float* __restrict__ bs,
                       const float* __restrict__ g2, const float* __restrict__ b2,
                       const float* __restrict__ g3, const float* __restrict__ b3,
                       const float* __restrict__ g4, const float* __restrict__ b4,
                       float* __restrict__ pr) {
  __shared__ float tot[70];
  int tx = threadIdx.x;   // 128
  if (tx < 70) {
    float acc = 0.f;
    #pragma unroll 8
    for (int i = 0; i < 128; ++i) acc += bs[tx*128 + i];
    tot[tx] = acc * INV_CNT;
  }
  __syncthreads();
  if (tx < 16) {
    float mean = tot[tx], var = tot[16+tx] - mean*mean;
    float sc = g2[tx]*rsqrtf(var + EPS);
    pr[128+tx] = sc; pr[144+tx] = fmaf(-mean, sc, b2[tx]);
  } else if (tx < 32) {
    int d = tx-16;
    float mean = tot[32+d], var = tot[48+d] - mean*mean;
    float sc = g3[d]*rsqrtf(var + EPS);
    pr[160+d] = sc; pr[176+d] = fmaf(-mean, sc, b3[d]);
  } else if (tx < 35) {
    int d = tx-32;
    float mean = tot[64+d], var = tot[67+d] - mean*mean;
    float sc = g4[d]*rsqrtf(var + EPS);
    pr[192+d] = sc; pr[195+d] = fmaf(-mean, sc, b4[d]);
  }
}

// ---- K5: flash attention, 4 rows/thread, 16-way column split ---------------
// blk: b = blk>>6, rc = (blk>>4)&3, cb = blk&15; 512 blocks = 2/CU
__global__ __launch_bounds__(256, 2) void k5_attn(
    const float* __restrict__ qp, const float* __restrict__ kp,
    const float* __restrict__ vp, const float* __restrict__ pr,
    float* __restrict__ pm, float* __restrict__ pl,
    float* __restrict__ pa0, float* __restrict__ pa1, float* __restrict__ pa2) {
  __shared__ float4 qvs[128*5];    // [mm][20 floats]: q0..15, v0..2, pad
  __shared__ float spr[70];
  int tx = threadIdx.x;
  if (tx < 70) spr[tx] = pr[128 + tx];
  int b  = blockIdx.x >> 6;
  int rc = (blockIdx.x >> 4) & 3;
  int cb = blockIdx.x & 15;
  int n0 = rc*1024 + tx;           // rows n0 + 256*r
  __syncthreads();
  float kv[64];
  #pragma unroll
  for (int r = 0; r < 4; ++r)
    #pragma unroll
    for (int d = 0; d < 16; ++d) {
      float t = fmaf(kp[(size_t)(b*16+d)*NN + n0 + r*256], spr[32+d], spr[48+d]);
      kv[r*16+d] = fmaxf(t, 0.f);
    }
  float m[4] = {0,0,0,0}, l[4] = {0,0,0,0};
  float a0[4] = {0,0,0,0}, a1[4] = {0,0,0,0}, a2[4] = {0,0,0,0};
  int c0 = cb << 8;                // 256 columns per block
  for (int m0 = c0; m0 < c0 + 256; m0 += 128) {
    __syncthreads();
    // stage q||v via b128 writes: item (mm, j): quad-group (5mm+j)%8 spread
    for (int i = tx; i < 640; i += 256) {
      int mm = i & 127, j = i >> 7;
      float4 t;
      if (j < 4) {
        int d = 4*j;
        t.x = fmaxf(fmaf(qp[(size_t)(b*16+d+0)*NN + m0 + mm], spr[d+0], spr[16+d+0]), 0.f);
        t.y = fmaxf(fmaf(qp[(size_t)(b*16+d+1)*NN + m0 + mm], spr[d+1], spr[16+d+1]), 0.f);
        t.z = fmaxf(fmaf(qp[(size_t)(b*16+d+2)*NN + m0 + mm], spr[d+2], spr[16+d+2]), 0.f);
        t.w = fmaxf(fmaf(qp[(size_t)(b*16+d+3)*NN + m0 + mm], spr[d+3], spr[16+d+3]), 0.f);
      } else {
        t.x = fmaxf(fmaf(vp[(size_t)(b*3+0)*NN + m0 + mm], spr[64], spr[67]), 0.f);
        t.y = fmaxf(fmaf(vp[(size_t)(b*3+1)*NN + m0 + mm], spr[65], spr[68]), 0.f);
        t.z = fmaxf(fmaf(vp[(size_t)(b*3+2)*NN + m0 + mm], spr[66], spr[69]), 0.f);
        t.w = 0.f;
      }
      qvs[mm*5 + j] = t;
    }
    __syncthreads();
    const float4* qv4 = (const float4*)qvs;
    #pragma unroll 2
    for (int mm = 0; mm < 128; ++mm) {
      float4 q0 = qv4[mm*5+0], q1 = qv4[mm*5+1], q2 = qv4[mm*5+2], q3 = qv4[mm*5+3];
      float4 vvv = qv4[mm*5+4];
      #pragma unroll
      for (int r = 0; r < 4; ++r) {
        float t0 = kv[r*16+0]*q0.x, t1 = kv[r*16+1]*q0.y;
        float t2 = kv[r*16+2]*q0.z, t3 = kv[r*16+3]*q0.w;
        t0 = fmaf(kv[r*16+4],  q1.x, t0); t1 = fmaf(kv[r*16+5],  q1.y, t1);
        t2 = fmaf(kv[r*16+6],  q1.z, t2); t3 = fmaf(kv[r*16+7],  q1.w, t3);
        t0 = fmaf(kv[r*16+8],  q2.x, t0); t1 = fmaf(kv[r*16+9],  q2.y, t1);
        t2 = fmaf(kv[r*16+10], q2.z, t2); t3 = fmaf(kv[r*16+11], q2.w, t3);
        t0 = fmaf(kv[r*16+12], q3.x, t0); t1 = fmaf(kv[r*16+13], q3.y, t1);
        t2 = fmaf(kv[r*16+14], q3.z, t2); t3 = fmaf(kv[r*16+15], q3.w, t3);
        float s = (t0+t1)+(t2+t3);
        float pw = __expf(s - m[r]);
        if (s - m[r] > 8.f) {            // rare rescale (defer-max, THR=8)
          float cc = __expf(m[r] - s);
          l[r] *= cc; a0[r] *= cc; a1[r] *= cc; a2[r] *= cc; m[r] = s; pw = 1.f;
        }
        l[r] += pw;
        a0[r] = fmaf(pw, vvv.x, a0[r]);
        a1[r] = fmaf(pw, vvv.y, a1[r]);
        a2[r] = fmaf(pw, vvv.z, a2[r]);
      }
    }
  }
  #pragma unroll
  for (int r = 0; r < 4; ++r) {
    size_t row = (size_t)cb*32768 + b*4096 + n0 + r*256;
    pm[row] = m[r]; pl[row] = l[r];
    pa0[row] = a0[r]; pa1[row] = a1[r]; pa2[row] = a2[r];
  }
}

// ---- K6: merge 16 column-chunk partials + epilogue -------------------------
__global__ __launch_bounds__(256) void k6_merge(
    const float* __restrict__ pm, const float* __restrict__ pl,
    const float* __restrict__ pa0, const float* __restrict__ pa1,
    const float* __restrict__ pa2, const float* __restrict__ x,
    const float* __restrict__ alpha, float* __restrict__ out) {
  int row = blockIdx.x*256 + threadIdx.x;   // 0..32767
  float M = 0.f, L = 0.f, A0 = 0.f, A1 = 0.f, A2 = 0.f;
  #pragma unroll
  for (int cb = 0; cb < 16; ++cb) {
    size_t i = (size_t)cb*32768 + row;
    float pmv = pm[i];
    float mn = fmaxf(M, pmv);
    float c1 = __expf(M - mn), c2 = __expf(pmv - mn);
    L  = L*c1  + pl[i]*c2;
    A0 = A0*c1 + pa0[i]*c2;
    A1 = A1*c1 + pa1[i]*c2;
    A2 = A2*c1 + pa2[i]*c2;
    M = mn;
  }
  int b = row >> 12, n = row & 4095;
  float inv = 1.f / L, al = alpha[0];
  out[(size_t)(b*3+0)*NN + n] = fmaf(al, A0*inv, x[(size_t)(b*3+0)*NN + n]);
  out[(size_t)(b*3+1)*NN + n] = fmaf(al, A1*inv, x[(size_t)(b*3+1)*NN + n]);
  out[(size_t)(b*3+2)*NN + n] = fmaf(al, A2*inv, x[(size_t)(b*3+2)*NN + n]);
}

extern "C" void kernel_launch(void* const* d_in, const int* in_sizes, int n_in,
                              void* d_out, int out_size, void* d_ws, size_t ws_size,
                              hipStream_t stream) {
  const float* x    = (const float*)d_in[0];
  const float* w1   = (const float*)d_in[1];
  const float* g1   = (const float*)d_in[2];
  const float* b1   = (const float*)d_in[3];
  const float* w2   = (const float*)d_in[4];
  const float* wq   = (const float*)d_in[5];
  const float* g2   = (const float*)d_in[6];
  const float* b2   = (const float*)d_in[7];
  const float* wk   = (const float*)d_in[8];
  const float* g3   = (const float*)d_in[9];
  const float* b3   = (const float*)d_in[10];
  const float* wv   = (const float*)d_in[11];
  const float* g4   = (const float*)d_in[12];
  const float* b4   = (const float*)d_in[13];
  const float* alpha= (const float*)d_in[14];
  float* out = (float*)d_out;
  float* ws  = (float*)d_ws;

  float* qpre = ws + OFF_QP;
  float* kpre = ws + OFF_KP;
  float* vpre = ws + OFF_VP;
  float* pr   = ws + OFF_PR;
  float* w1p  = ws + OFF_W1P;
  float* wt2  = ws + OFF_WT2;
  float* xp   = ws + OFF_XP;
  float* bst  = ws + OFF_BS;
  float* pm   = ws + OFF_PM;
  float* pl   = ws + OFF_PL;
  float* pa0  = ws + OFF_PA0;
  float* pa1  = ws + OFF_PA1;
  float* pa2  = ws + OFF_PA2;

  k0_xmom<<<128, 256, 0, stream>>>(x, xp);
  f0_wcomb<<<1, 256, 0, stream>>>(w2, wq, wk, wv, wt2);
  f1_fin<<<1, 64, 0, stream>>>(xp, w1, g1, b1, w1p);
  k3_qkv<<<128, 256, 0, stream>>>(x, w1p, wt2, qpre, kpre, vpre, bst);
  f2_fin<<<1, 128, 0, stream>>>(bst, g2, b2, g3, b3, g4, b4, pr);
  k5_attn<<<512, 256, 0, stream>>>(qpre, kpre, vpre, pr, pm, pl, pa0, pa1, pa2);
  k6_merge<<<128, 256, 0, stream>>>(pm, pl, pa0, pa1, pa2, x, alpha, out);
}

// Round 10
// 128.009 us; speedup vs baseline: 8.7821x; 1.3585x over previous
//
#include <hip/hip_runtime.h>

#define EPS 1e-5f
constexpr int NN = 4096;
constexpr float INV_CNT = 1.0f / (8.0f * 4096.0f);

typedef __attribute__((ext_vector_type(8))) short bf16x8;
typedef __attribute__((ext_vector_type(4))) float f32x4;

// workspace layout (float offsets)
constexpr size_t OFF_QPT = 0;        // 524288  q pre-act, point-major [p][16]
constexpr size_t OFF_KPT = 524288;   // 524288
constexpr size_t OFF_VPT = 1048576;  // 131072  v pre-act, [p][4]
constexpr size_t OFF_PR  = 1179648;  // 256
constexpr size_t OFF_W1P = 1179904;  // 256
constexpr size_t OFF_WT2 = 1180160;  // 2304
constexpr size_t OFF_XP  = 1182464;  // 1152
constexpr size_t OFF_BS  = 1183616;  // 8960
constexpr size_t OFF_QH  = 1192576;  // 262144 (bf16 hi, [p][16] = 2 uint4/p)
constexpr size_t OFF_QL  = 1454720;  // 262144
constexpr size_t OFF_KH  = 1716864;  // 262144
constexpr size_t OFF_KL  = 1979008;  // 262144
constexpr size_t OFF_VB  = 2241152;  // 131072 (BN'd v, float4/p)
constexpr size_t OFF_PL  = 2372224;  // 2*32768 partial l
constexpr size_t OFF_PA0 = 2437760;
constexpr size_t OFF_PA1 = 2503296;
constexpr size_t OFF_PA2 = 2568832;
constexpr size_t OFF_PM  = 2634368;  // 2*32768 partial max; end 2699904 = 10.8 MB

// ---- K0: x moments -> block partials ---------------------------------------
__global__ __launch_bounds__(256) void k0_xmom(const float* __restrict__ x,
                                               float* __restrict__ xpart) {
  __shared__ float sred[36];
  int tx = threadIdx.x;
  int idx = blockIdx.x * 256 + tx;
  int b = idx >> 12, n = idx & 4095;
  float x0 = x[(size_t)(b*3+0)*NN + n];
  float x1 = x[(size_t)(b*3+1)*NN + n];
  float x2 = x[(size_t)(b*3+2)*NN + n];
  float m[9] = {x0, x1, x2, x0*x0, x0*x1, x0*x2, x1*x1, x1*x2, x2*x2};
  #pragma unroll
  for (int off = 32; off; off >>= 1) {
    #pragma unroll
    for (int j = 0; j < 9; ++j) m[j] += __shfl_xor(m[j], off);
  }
  int w = tx >> 6;
  if ((tx & 63) == 0) {
    #pragma unroll
    for (int j = 0; j < 9; ++j) sred[w*9+j] = m[j];
  }
  __syncthreads();
  if (tx < 9) xpart[tx*128 + blockIdx.x] = sred[tx] + sred[9+tx] + sred[18+tx] + sred[27+tx];
}

// ---- F0: combined weights Wq2 = wq@w2 etc., c-major [c][36] ----------------
__global__ __launch_bounds__(256) void f0_wcomb(const float* __restrict__ w2,
                                                const float* __restrict__ wq,
                                                const float* __restrict__ wk,
                                                const float* __restrict__ wv,
                                                float* __restrict__ wt2) {
  __shared__ float w2s[8192];
  __shared__ float wr[4480];
  int tx = threadIdx.x;
  for (int i = tx; i < 8192; i += 256) w2s[i] = w2[i];
  for (int i = tx; i < 2048; i += 256) { wr[i] = wq[i]; wr[2048+i] = wk[i]; }
  for (int i = tx; i < 384; i += 256) wr[4096+i] = wv[i];
  __syncthreads();
  for (int e = tx; e < 2240; e += 256) {
    int j = e >> 6, c = e & 63;
    float s = 0.f;
    #pragma unroll 4
    for (int o = 0; o < 128; ++o) s = fmaf(wr[j*128+o], w2s[o*64+c], s);
    wt2[c*36 + j] = s;
  }
}

// ---- F1: reduce x-moment partials, fold BN1 into w1 ------------------------
__global__ void f1_fin(const float* __restrict__ xpart, const float* __restrict__ w1,
                       const float* __restrict__ g1, const float* __restrict__ b1,
                       float* __restrict__ w1p) {
  __shared__ float mom[9];
  int tx = threadIdx.x;   // 64
  if (tx < 9) {
    float acc = 0.f;
    #pragma unroll 8
    for (int i = 0; i < 128; ++i) acc += xpart[tx*128 + i];
    mom[tx] = acc * INV_CNT;
  }
  __syncthreads();
  int c = tx;
  float a = w1[c*3], b_ = w1[c*3+1], d = w1[c*3+2];
  float mean = a*mom[0] + b_*mom[1] + d*mom[2];
  float e2 = a*a*mom[3] + b_*b_*mom[6] + d*d*mom[8]
           + 2.f*(a*b_*mom[4] + a*d*mom[5] + b_*d*mom[7]);
  float sc = g1[c] * rsqrtf(e2 - mean*mean + EPS);
  w1p[c*4+0] = a*sc; w1p[c*4+1] = b_*sc; w1p[c*4+2] = d*sc;
  w1p[c*4+3] = fmaf(-mean, sc, b1[c]);
}

// ---- K3: per point -> qa/ka/va (point-major) + block-partial stats ---------
__global__ __launch_bounds__(256, 2) void k3_qkv(
    const float* __restrict__ x, const float* __restrict__ w1p,
    const float* __restrict__ wt2,
    float* __restrict__ qpT, float* __restrict__ kpT, float* __restrict__ vpT,
    float* __restrict__ bs) {
  __shared__ float4 w1s[64];
  __shared__ float4 wt2s[576];
  __shared__ float sred[280];
  int tx = threadIdx.x;
  for (int i = tx; i < 576; i += 256) wt2s[i] = ((const float4*)wt2)[i];
  if (tx < 64) w1s[tx] = ((const float4*)w1p)[tx];
  __syncthreads();
  int idx = blockIdx.x*256 + tx;
  int b = idx >> 12, n = idx & 4095;
  float x0 = x[(size_t)(b*3+0)*NN + n];
  float x1 = x[(size_t)(b*3+1)*NN + n];
  float x2 = x[(size_t)(b*3+2)*NN + n];
  float qa[16] = {}, ka[16] = {};
  float va0 = 0.f, va1 = 0.f, va2 = 0.f;
  #pragma unroll 4
  for (int c = 0; c < 64; ++c) {
    float4 w = w1s[c];
    float h = fmaf(w.x, x0, fmaf(w.y, x1, fmaf(w.z, x2, w.w)));
    h = h > 0.f ? h : 0.2f*h;
    #pragma unroll
    for (int j = 0; j < 4; ++j) {
      float4 A = wt2s[c*9 + j];
      qa[4*j+0] = fmaf(A.x, h, qa[4*j+0]);
      qa[4*j+1] = fmaf(A.y, h, qa[4*j+1]);
      qa[4*j+2] = fmaf(A.z, h, qa[4*j+2]);
      qa[4*j+3] = fmaf(A.w, h, qa[4*j+3]);
      float4 B = wt2s[c*9 + 4 + j];
      ka[4*j+0] = fmaf(B.x, h, ka[4*j+0]);
      ka[4*j+1] = fmaf(B.y, h, ka[4*j+1]);
      ka[4*j+2] = fmaf(B.z, h, ka[4*j+2]);
      ka[4*j+3] = fmaf(B.w, h, ka[4*j+3]);
    }
    float4 V = wt2s[c*9 + 8];
    va0 = fmaf(V.x, h, va0); va1 = fmaf(V.y, h, va1); va2 = fmaf(V.z, h, va2);
  }
  float4* qo = (float4*)(qpT + (size_t)idx*16);
  float4* ko = (float4*)(kpT + (size_t)idx*16);
  #pragma unroll
  for (int j = 0; j < 4; ++j) {
    qo[j] = make_float4(qa[4*j], qa[4*j+1], qa[4*j+2], qa[4*j+3]);
    ko[j] = make_float4(ka[4*j], ka[4*j+1], ka[4*j+2], ka[4*j+3]);
  }
  ((float4*)vpT)[idx] = make_float4(va0, va1, va2, 0.f);
  int w = tx >> 6;
  bool lead = ((tx & 63) == 0);
  #pragma unroll
  for (int d = 0; d < 16; ++d) {
    float s = qa[d], q = qa[d]*qa[d];
    #pragma unroll
    for (int off = 32; off; off >>= 1) { s += __shfl_xor(s, off); q += __shfl_xor(q, off); }
    if (lead) { sred[w*70 + d] = s; sred[w*70 + 16 + d] = q; }
    s = ka[d]; q = ka[d]*ka[d];
    #pragma unroll
    for (int off = 32; off; off >>= 1) { s += __shfl_xor(s, off); q += __shfl_xor(q, off); }
    if (lead) { sred[w*70 + 32 + d] = s; sred[w*70 + 48 + d] = q; }
  }
  float vv[3] = {va0, va1, va2};
  #pragma unroll
  for (int d = 0; d < 3; ++d) {
    float s = vv[d], q = vv[d]*vv[d];
    #pragma unroll
    for (int off = 32; off; off >>= 1) { s += __shfl_xor(s, off); q += __shfl_xor(q, off); }
    if (lead) { sred[w*70 + 64 + d] = s; sred[w*70 + 67 + d] = q; }
  }
  __syncthreads();
  if (tx < 70)
    bs[tx*128 + blockIdx.x] = sred[tx] + sred[70+tx] + sred[140+tx] + sred[210+tx];
}

// ---- F2: reduce stat partials, finalize BN2/3/4 ----------------------------
__global__ void f2_fin(const float* __restrict__ bs,
                       const float* __restrict__ g2, const float* __restrict__ b2,
                       const float* __restrict__ g3, const float* __restrict__ b3,
                       const float* __restrict__ g4, const float* __restrict__ b4,
                       float* __restrict__ pr) {
  __shared__ float tot[70];
  int tx = threadIdx.x;   // 128
  if (tx < 70) {
    float acc = 0.f;
    #pragma unroll 8
    for (int i = 0; i < 128; ++i) acc += bs[tx*128 + i];
    tot[tx] = acc * INV_CNT;
  }
  __syncthreads();
  if (tx < 16) {
    float mean = tot[tx], var = tot[16+tx] - mean*mean;
    float sc = g2[tx]*rsqrtf(var + EPS);
    pr[128+tx] = sc; pr[144+tx] = fmaf(-mean, sc, b2[tx]);
  } else if (tx < 32) {
    int d = tx-16;
    float mean = tot[32+d], var = tot[48+d] - mean*mean;
    float sc = g3[d]*rsqrtf(var + EPS);
    pr[160+d] = sc; pr[176+d] = fmaf(-mean, sc, b3[d]);
  } else if (tx < 35) {
    int d = tx-32;
    float mean = tot[64+d], var = tot[67+d] - mean*mean;
    float sc = g4[d]*rsqrtf(var + EPS);
    pr[192+d] = sc; pr[195+d] = fmaf(-mean, sc, b4[d]);
  }
}

// ---- K4: BN+ReLU, hi/lo bf16 split, point-major packing --------------------
__global__ __launch_bounds__(256) void k4_prep(
    const float* __restrict__ qpT, const float* __restrict__ kpT,
    const float* __restrict__ vpT, const float* __restrict__ pr,
    uint4* __restrict__ qh, uint4* __restrict__ ql,
    uint4* __restrict__ kh, uint4* __restrict__ kl,
    float4* __restrict__ vb) {
  __shared__ float spr[70];
  int tx = threadIdx.x;
  if (tx < 70) spr[tx] = pr[128 + tx];
  __syncthreads();
  int p = blockIdx.x*256 + tx;
  float qv[16], kv[16];
  const float4* q4 = (const float4*)(qpT + (size_t)p*16);
  const float4* k4p = (const float4*)(kpT + (size_t)p*16);
  #pragma unroll
  for (int j = 0; j < 4; ++j) {
    float4 tq = q4[j], tk = k4p[j];
    qv[4*j] = tq.x; qv[4*j+1] = tq.y; qv[4*j+2] = tq.z; qv[4*j+3] = tq.w;
    kv[4*j] = tk.x; kv[4*j+1] = tk.y; kv[4*j+2] = tk.z; kv[4*j+3] = tk.w;
  }
  #pragma unroll
  for (int d = 0; d < 16; ++d) {
    qv[d] = fmaxf(fmaf(qv[d], spr[d],    spr[16+d]), 0.f);
    kv[d] = fmaxf(fmaf(kv[d], spr[32+d], spr[48+d]), 0.f);
  }
  unsigned qhw[8], qlw[8], khw[8], klw[8];
  #pragma unroll
  for (int j = 0; j < 8; ++j) {
    unsigned u0 = __float_as_uint(qv[2*j]),   u1 = __float_as_uint(qv[2*j+1]);
    unsigned h0 = u0 & 0xFFFF0000u, h1 = u1 & 0xFFFF0000u;
    float l0 = qv[2*j] - __uint_as_float(h0);
    float l1 = qv[2*j+1] - __uint_as_float(h1);
    qhw[j] = (h0 >> 16) | h1;
    qlw[j] = (__float_as_uint(l0) >> 16) | (__float_as_uint(l1) & 0xFFFF0000u);
    u0 = __float_as_uint(kv[2*j]); u1 = __float_as_uint(kv[2*j+1]);
    h0 = u0 & 0xFFFF0000u; h1 = u1 & 0xFFFF0000u;
    l0 = kv[2*j] - __uint_as_float(h0);
    l1 = kv[2*j+1] - __uint_as_float(h1);
    khw[j] = (h0 >> 16) | h1;
    klw[j] = (__float_as_uint(l0) >> 16) | (__float_as_uint(l1) & 0xFFFF0000u);
  }
  qh[(size_t)p*2+0] = make_uint4(qhw[0], qhw[1], qhw[2], qhw[3]);
  qh[(size_t)p*2+1] = make_uint4(qhw[4], qhw[5], qhw[6], qhw[7]);
  ql[(size_t)p*2+0] = make_uint4(qlw[0], qlw[1], qlw[2], qlw[3]);
  ql[(size_t)p*2+1] = make_uint4(qlw[4], qlw[5], qlw[6], qlw[7]);
  kh[(size_t)p*2+0] = make_uint4(khw[0], khw[1], khw[2], khw[3]);
  kh[(size_t)p*2+1] = make_uint4(khw[4], khw[5], khw[6], khw[7]);
  kl[(size_t)p*2+0] = make_uint4(klw[0], klw[1], klw[2], klw[3]);
  kl[(size_t)p*2+1] = make_uint4(klw[4], klw[5], klw[6], klw[7]);
  float4 vv = ((const float4*)vpT)[p];
  vb[p] = make_float4(fmaxf(fmaf(vv.x, spr[64], spr[67]), 0.f),
                      fmaxf(fmaf(vv.y, spr[65], spr[68]), 0.f),
                      fmaxf(fmaf(vv.z, spr[66], spr[69]), 0.f), 0.f);
}

// ---- K5: MFMA attention (16x16x32) + PER-ROW defer-max online softmax ------
// A = K rows (n), B = Q cols (m); MFMA1: A=[kh;kl], B=[qh;qh]; MFMA2:
// A=[kh;0], B=[ql;ql]. C: col=lane&15 (m), row=(lane>>4)*4+reg (n).
// Per-ROW running max M[r] (R4-proven semantics; defer THR=8 => l[r] >= e^-8
// per chunk, no underflow-to-zero; exp arg <= 8, no overflow).
__global__ __launch_bounds__(128, 4) void k5_attn(
    const uint4* __restrict__ qh, const uint4* __restrict__ ql,
    const uint4* __restrict__ kh, const uint4* __restrict__ kl,
    const float4* __restrict__ vb,
    float* __restrict__ pm, float* __restrict__ pl, float* __restrict__ pa0,
    float* __restrict__ pa1, float* __restrict__ pa2) {
  int tx = threadIdx.x;
  int cb = blockIdx.x & 1;
  int rb = blockIdx.x >> 1;
  int b  = rb >> 7;
  int rc = rb & 127;
  int w = tx >> 6, lane = tx & 63;
  int qrow = lane & 15, kg = lane >> 4, kg1 = kg & 1;
  int n0 = rc*32 + w*16;
  size_t pbase = (size_t)b*4096;
  size_t ap = (pbase + n0 + qrow)*2 + kg1;
  bf16x8 aF  = (kg < 2) ? *(const bf16x8*)&kh[ap] : *(const bf16x8*)&kl[ap];
  bf16x8 zf = {0,0,0,0,0,0,0,0};
  bf16x8 aF2 = (kg < 2) ? aF : zf;
  f32x4 zero4 = {0.f, 0.f, 0.f, 0.f};
  float M[4] = {0,0,0,0};   // per-row running max (scores >= 0)
  float l[4] = {0,0,0,0}, a0[4] = {0,0,0,0}, a1[4] = {0,0,0,0}, a2[4] = {0,0,0,0};
  size_t cbase = pbase + (size_t)cb*2048;
  #pragma unroll 2
  for (int ct = 0; ct < 128; ++ct) {
    size_t bp = cbase + ct*16 + qrow;
    bf16x8 bqh = *(const bf16x8*)&qh[bp*2 + kg1];
    bf16x8 bql = *(const bf16x8*)&ql[bp*2 + kg1];
    f32x4 c = __builtin_amdgcn_mfma_f32_16x16x32_bf16(aF,  bqh, zero4, 0, 0, 0);
    c = __builtin_amdgcn_mfma_f32_16x16x32_bf16(aF2, bql, c, 0, 0, 0);
    float4 v = vb[bp];
    #pragma unroll
    for (int r = 0; r < 4; ++r) {
      float d = c[r] - M[r];
      float pw = __expf(d);
      if (d > 8.f) {                     // rare per-row rescale (defer-max)
        float cc = __expf(-d);
        l[r] *= cc; a0[r] *= cc; a1[r] *= cc; a2[r] *= cc;
        M[r] = c[r]; pw = 1.f;
      }
      l[r] += pw;
      a0[r] = fmaf(pw, v.x, a0[r]);
      a1[r] = fmaf(pw, v.y, a1[r]);
      a2[r] = fmaf(pw, v.z, a2[r]);
    }
  }
  // per-row merge of the 16 column-phases (lane bits 0-3; kg preserved)
  #pragma unroll
  for (int r = 0; r < 4; ++r) {
    float Mh = M[r];
    #pragma unroll
    for (int off = 1; off <= 8; off <<= 1) Mh = fmaxf(Mh, __shfl_xor(Mh, off));
    float s = __expf(M[r] - Mh);
    l[r] *= s; a0[r] *= s; a1[r] *= s; a2[r] *= s;
    M[r] = Mh;
  }
  #pragma unroll
  for (int off = 1; off <= 8; off <<= 1) {
    #pragma unroll
    for (int r = 0; r < 4; ++r) {
      l[r]  += __shfl_xor(l[r],  off);
      a0[r] += __shfl_xor(a0[r], off);
      a1[r] += __shfl_xor(a1[r], off);
      a2[r] += __shfl_xor(a2[r], off);
    }
  }
  size_t base = (size_t)cb*32768 + pbase + n0 + kg*4;
  #pragma unroll
  for (int r = 0; r < 4; ++r) {
    if (qrow == r) {
      pm[base+r]  = M[r]; pl[base+r] = l[r];
      pa0[base+r] = a0[r]; pa1[base+r] = a1[r]; pa2[base+r] = a2[r];
    }
  }
}

// ---- K6: max-merge 2 column-chunk partials + epilogue ----------------------
__global__ __launch_bounds__(256) void k6_merge(
    const float* __restrict__ pm, const float* __restrict__ pl,
    const float* __restrict__ pa0, const float* __restrict__ pa1,
    const float* __restrict__ pa2, const float* __restrict__ x,
    const float* __restrict__ alpha, float* __restrict__ out) {
  int row = blockIdx.x*256 + threadIdx.x;   // 0..32767
  float m0 = pm[row], m1 = pm[32768+row];
  float M = fmaxf(m0, m1);
  float c0 = __expf(m0 - M), c1 = __expf(m1 - M);
  float L  = pl[row]*c0  + pl[32768+row]*c1;
  float A0 = pa0[row]*c0 + pa0[32768+row]*c1;
  float A1 = pa1[row]*c0 + pa1[32768+row]*c1;
  float A2 = pa2[row]*c0 + pa2[32768+row]*c1;
  int b = row >> 12, n = row & 4095;
  float inv = 1.f / L, al = alpha[0];
  out[(size_t)(b*3+0)*NN + n] = fmaf(al, A0*inv, x[(size_t)(b*3+0)*NN + n]);
  out[(size_t)(b*3+1)*NN + n] = fmaf(al, A1*inv, x[(size_t)(b*3+1)*NN + n]);
  out[(size_t)(b*3+2)*NN + n] = fmaf(al, A2*inv, x[(size_t)(b*3+2)*NN + n]);
}

extern "C" void kernel_launch(void* const* d_in, const int* in_sizes, int n_in,
                              void* d_out, int out_size, void* d_ws, size_t ws_size,
                              hipStream_t stream) {
  const float* x    = (const float*)d_in[0];
  const float* w1   = (const float*)d_in[1];
  const float* g1   = (const float*)d_in[2];
  const float* b1   = (const float*)d_in[3];
  const float* w2   = (const float*)d_in[4];
  const float* wq   = (const float*)d_in[5];
  const float* g2   = (const float*)d_in[6];
  const float* b2   = (const float*)d_in[7];
  const float* wk   = (const float*)d_in[8];
  const float* g3   = (const float*)d_in[9];
  const float* b3   = (const float*)d_in[10];
  const float* wv   = (const float*)d_in[11];
  const float* g4   = (const float*)d_in[12];
  const float* b4   = (const float*)d_in[13];
  const float* alpha= (const float*)d_in[14];
  float* out = (float*)d_out;
  float* ws  = (float*)d_ws;

  float* qpT = ws + OFF_QPT;
  float* kpT = ws + OFF_KPT;
  float* vpT = ws + OFF_VPT;
  float* pr  = ws + OFF_PR;
  float* w1p = ws + OFF_W1P;
  float* wt2 = ws + OFF_WT2;
  float* xp  = ws + OFF_XP;
  float* bst = ws + OFF_BS;
  uint4* qhb = (uint4*)(ws + OFF_QH);
  uint4* qlb = (uint4*)(ws + OFF_QL);
  uint4* khb = (uint4*)(ws + OFF_KH);
  uint4* klb = (uint4*)(ws + OFF_KL);
  float4* vbb = (float4*)(ws + OFF_VB);
  float* pms = ws + OFF_PM;
  float* pls = ws + OFF_PL;
  float* pa0 = ws + OFF_PA0;
  float* pa1 = ws + OFF_PA1;
  float* pa2 = ws + OFF_PA2;

  k0_xmom<<<128, 256, 0, stream>>>(x, xp);
  f0_wcomb<<<1, 256, 0, stream>>>(w2, wq, wk, wv, wt2);
  f1_fin<<<1, 64, 0, stream>>>(xp, w1, g1, b1, w1p);
  k3_qkv<<<128, 256, 0, stream>>>(x, w1p, wt2, qpT, kpT, vpT, bst);
  f2_fin<<<1, 128, 0, stream>>>(bst, g2, b2, g3, b3, g4, b4, pr);
  k4_prep<<<128, 256, 0, stream>>>(qpT, kpT, vpT, pr, qhb, qlb, khb, klb, vbb);
  k5_attn<<<2048, 128, 0, stream>>>(qhb, qlb, khb, klb, vbb, pms, pls, pa0, pa1, pa2);
  k6_merge<<<128, 256, 0, stream>>>(pms, pls, pa0, pa1, pa2, x, alpha, out);
}

// Round 12
// 121.292 us; speedup vs baseline: 9.2685x; 1.0554x over previous
//
#include <hip/hip_runtime.h>

#define EPS 1e-5f
constexpr int NN = 4096;
constexpr float INV_CNT = 1.0f / (8.0f * 4096.0f);
constexpr float LOG2E = 1.44269504f;

typedef __attribute__((ext_vector_type(8))) short bf16x8;
typedef __attribute__((ext_vector_type(4))) float f32x4;
typedef __attribute__((ext_vector_type(4))) _Float16 f16x4;

// workspace layout (float offsets)
constexpr size_t OFF_QPT = 0;        // 524288  q pre-act, point-major [p][16]
constexpr size_t OFF_KPT = 524288;   // 524288
constexpr size_t OFF_VPT = 1048576;  // 131072  v pre-act, [p][4]
constexpr size_t OFF_WT2 = 1179648;  // 2304
constexpr size_t OFF_XP  = 1181952;  // 1152
constexpr size_t OFF_BS  = 1183104;  // 70*256 = 17920
constexpr size_t OFF_QH  = 1201024;  // 262144 (bf16 hi, [p][16] = 2 uint4/p)
constexpr size_t OFF_QL  = 1463168;  // 262144
constexpr size_t OFF_KH  = 1725312;  // 262144
constexpr size_t OFF_KL  = 1987456;  // 262144
constexpr size_t OFF_VFH = 2249600;  // 65536 fl = 4ch x 32768 fp16 (v0,v1,v2,ones)
constexpr size_t OFF_PL  = 2315136;  // 4*32768
constexpr size_t OFF_PA0 = 2446208;
constexpr size_t OFF_PA1 = 2577280;
constexpr size_t OFF_PA2 = 2708352;
constexpr size_t OFF_PM  = 2839424;  // 4*32768; end 2970496 = 11.9 MB

// ---- kA: blocks 0-127: x moments; block 128: combined weights --------------
__global__ __launch_bounds__(256) void kA_mom_wcomb(
    const float* __restrict__ x, float* __restrict__ xpart,
    const float* __restrict__ w2, const float* __restrict__ wq,
    const float* __restrict__ wk, const float* __restrict__ wv,
    float* __restrict__ wt2) {
  __shared__ float w2s[8192];
  __shared__ float wr[4480];
  __shared__ float sred[36];
  int tx = threadIdx.x;
  if (blockIdx.x < 128) {
    int idx = blockIdx.x * 256 + tx;
    int b = idx >> 12, n = idx & 4095;
    float x0 = x[(size_t)(b*3+0)*NN + n];
    float x1 = x[(size_t)(b*3+1)*NN + n];
    float x2 = x[(size_t)(b*3+2)*NN + n];
    float m[9] = {x0, x1, x2, x0*x0, x0*x1, x0*x2, x1*x1, x1*x2, x2*x2};
    #pragma unroll
    for (int off = 32; off; off >>= 1) {
      #pragma unroll
      for (int j = 0; j < 9; ++j) m[j] += __shfl_xor(m[j], off);
    }
    int w = tx >> 6;
    if ((tx & 63) == 0) {
      #pragma unroll
      for (int j = 0; j < 9; ++j) sred[w*9+j] = m[j];
    }
    __syncthreads();
    if (tx < 9) xpart[tx*128 + blockIdx.x] = sred[tx] + sred[9+tx] + sred[18+tx] + sred[27+tx];
  } else {
    for (int i = tx; i < 8192; i += 256) w2s[i] = w2[i];
    for (int i = tx; i < 2048; i += 256) { wr[i] = wq[i]; wr[2048+i] = wk[i]; }
    for (int i = tx; i < 384; i += 256) wr[4096+i] = wv[i];
    __syncthreads();
    for (int e = tx; e < 2240; e += 256) {
      int j = e >> 6, c = e & 63;
      float s = 0.f;
      #pragma unroll 4
      for (int o = 0; o < 128; ++o) s = fmaf(wr[j*128+o], w2s[o*64+c], s);
      wt2[c*36 + j] = s;
    }
  }
}

// ---- kB: (f1 fused) per point -> qa/ka/va + block-partial stats ------------
__global__ __launch_bounds__(128) void kB_qkv(
    const float* __restrict__ x, const float* __restrict__ xpart,
    const float* __restrict__ w1, const float* __restrict__ g1,
    const float* __restrict__ b1, const float* __restrict__ wt2,
    float* __restrict__ qpT, float* __restrict__ kpT, float* __restrict__ vpT,
    float* __restrict__ bs) {
  __shared__ float4 w1s[64];
  __shared__ float4 wt2s[576];
  __shared__ float sred[140];
  __shared__ float mom[9];
  int tx = threadIdx.x;
  for (int i = tx; i < 576; i += 128) wt2s[i] = ((const float4*)wt2)[i];
  if (tx < 9) {
    float acc = 0.f;
    #pragma unroll 8
    for (int i = 0; i < 128; ++i) acc += xpart[tx*128 + i];
    mom[tx] = acc * INV_CNT;
  }
  __syncthreads();
  if (tx < 64) {
    int c = tx;
    float a = w1[c*3], b_ = w1[c*3+1], d = w1[c*3+2];
    float mean = a*mom[0] + b_*mom[1] + d*mom[2];
    float e2 = a*a*mom[3] + b_*b_*mom[6] + d*d*mom[8]
             + 2.f*(a*b_*mom[4] + a*d*mom[5] + b_*d*mom[7]);
    float sc = g1[c] * rsqrtf(e2 - mean*mean + EPS);
    w1s[c] = make_float4(a*sc, b_*sc, d*sc, fmaf(-mean, sc, b1[c]));
  }
  __syncthreads();
  int idx = blockIdx.x*128 + tx;
  int b = idx >> 12, n = idx & 4095;
  float x0 = x[(size_t)(b*3+0)*NN + n];
  float x1 = x[(size_t)(b*3+1)*NN + n];
  float x2 = x[(size_t)(b*3+2)*NN + n];
  float qa[16] = {}, ka[16] = {};
  float va0 = 0.f, va1 = 0.f, va2 = 0.f;
  #pragma unroll 4
  for (int c = 0; c < 64; ++c) {
    float4 w = w1s[c];
    float h = fmaf(w.x, x0, fmaf(w.y, x1, fmaf(w.z, x2, w.w)));
    h = h > 0.f ? h : 0.2f*h;
    #pragma unroll
    for (int j = 0; j < 4; ++j) {
      float4 A = wt2s[c*9 + j];
      qa[4*j+0] = fmaf(A.x, h, qa[4*j+0]);
      qa[4*j+1] = fmaf(A.y, h, qa[4*j+1]);
      qa[4*j+2] = fmaf(A.z, h, qa[4*j+2]);
      qa[4*j+3] = fmaf(A.w, h, qa[4*j+3]);
      float4 B = wt2s[c*9 + 4 + j];
      ka[4*j+0] = fmaf(B.x, h, ka[4*j+0]);
      ka[4*j+1] = fmaf(B.y, h, ka[4*j+1]);
      ka[4*j+2] = fmaf(B.z, h, ka[4*j+2]);
      ka[4*j+3] = fmaf(B.w, h, ka[4*j+3]);
    }
    float4 V = wt2s[c*9 + 8];
    va0 = fmaf(V.x, h, va0); va1 = fmaf(V.y, h, va1); va2 = fmaf(V.z, h, va2);
  }
  float4* qo = (float4*)(qpT + (size_t)idx*16);
  float4* ko = (float4*)(kpT + (size_t)idx*16);
  #pragma unroll
  for (int j = 0; j < 4; ++j) {
    qo[j] = make_float4(qa[4*j], qa[4*j+1], qa[4*j+2], qa[4*j+3]);
    ko[j] = make_float4(ka[4*j], ka[4*j+1], ka[4*j+2], ka[4*j+3]);
  }
  ((float4*)vpT)[idx] = make_float4(va0, va1, va2, 0.f);
  int w = tx >> 6;
  bool lead = ((tx & 63) == 0);
  #pragma unroll
  for (int d = 0; d < 16; ++d) {
    float s = qa[d], q = qa[d]*qa[d];
    #pragma unroll
    for (int off = 32; off; off >>= 1) { s += __shfl_xor(s, off); q += __shfl_xor(q, off); }
    if (lead) { sred[w*70 + d] = s; sred[w*70 + 16 + d] = q; }
    s = ka[d]; q = ka[d]*ka[d];
    #pragma unroll
    for (int off = 32; off; off >>= 1) { s += __shfl_xor(s, off); q += __shfl_xor(q, off); }
    if (lead) { sred[w*70 + 32 + d] = s; sred[w*70 + 48 + d] = q; }
  }
  float vv[3] = {va0, va1, va2};
  #pragma unroll
  for (int d = 0; d < 3; ++d) {
    float s = vv[d], q = vv[d]*vv[d];
    #pragma unroll
    for (int off = 32; off; off >>= 1) { s += __shfl_xor(s, off); q += __shfl_xor(q, off); }
    if (lead) { sred[w*70 + 64 + d] = s; sred[w*70 + 67 + d] = q; }
  }
  __syncthreads();
  if (tx < 70)
    bs[tx*256 + blockIdx.x] = sred[tx] + sred[70+tx];
}

// ---- kC: (f2 fused) BN+ReLU, q scaled by log2e, hi/lo split, v->fp16 -------
__global__ __launch_bounds__(256) void kC_prep(
    const float* __restrict__ qpT, const float* __restrict__ kpT,
    const float* __restrict__ vpT, const float* __restrict__ bs,
    const float* __restrict__ g2, const float* __restrict__ b2,
    const float* __restrict__ g3, const float* __restrict__ b3,
    const float* __restrict__ g4, const float* __restrict__ b4,
    uint4* __restrict__ qh, uint4* __restrict__ ql,
    uint4* __restrict__ kh, uint4* __restrict__ kl,
    _Float16* __restrict__ vfh) {
  __shared__ float tot[70];
  __shared__ float spr[70];
  int tx = threadIdx.x;
  if (tx < 70) {
    float acc = 0.f;
    #pragma unroll 8
    for (int i = 0; i < 256; ++i) acc += bs[tx*256 + i];
    tot[tx] = acc * INV_CNT;
  }
  __syncthreads();
  if (tx < 16) {
    float mean = tot[tx], var = tot[16+tx] - mean*mean;
    float sc = g2[tx]*rsqrtf(var + EPS);
    spr[tx] = sc * LOG2E;                                // q scaled to log2 domain
    spr[16+tx] = fmaf(-mean, sc, b2[tx]) * LOG2E;
  } else if (tx < 32) {
    int d = tx-16;
    float mean = tot[32+d], var = tot[48+d] - mean*mean;
    float sc = g3[d]*rsqrtf(var + EPS);
    spr[32+d] = sc; spr[48+d] = fmaf(-mean, sc, b3[d]);
  } else if (tx < 35) {
    int d = tx-32;
    float mean = tot[64+d], var = tot[67+d] - mean*mean;
    float sc = g4[d]*rsqrtf(var + EPS);
    spr[64+d] = sc; spr[67+d] = fmaf(-mean, sc, b4[d]);
  }
  __syncthreads();
  int p = blockIdx.x*256 + tx;
  float qv[16], kv[16];
  const float4* q4 = (const float4*)(qpT + (size_t)p*16);
  const float4* k4p = (const float4*)(kpT + (size_t)p*16);
  #pragma unroll
  for (int j = 0; j < 4; ++j) {
    float4 tq = q4[j], tk = k4p[j];
    qv[4*j] = tq.x; qv[4*j+1] = tq.y; qv[4*j+2] = tq.z; qv[4*j+3] = tq.w;
    kv[4*j] = tk.x; kv[4*j+1] = tk.y; kv[4*j+2] = tk.z; kv[4*j+3] = tk.w;
  }
  #pragma unroll
  for (int d = 0; d < 16; ++d) {
    qv[d] = fmaxf(fmaf(qv[d], spr[d],    spr[16+d]), 0.f);
    kv[d] = fmaxf(fmaf(kv[d], spr[32+d], spr[48+d]), 0.f);
  }
  unsigned qhw[8], qlw[8], khw[8], klw[8];
  #pragma unroll
  for (int j = 0; j < 8; ++j) {
    unsigned u0 = __float_as_uint(qv[2*j]),   u1 = __float_as_uint(qv[2*j+1]);
    unsigned h0 = u0 & 0xFFFF0000u, h1 = u1 & 0xFFFF0000u;
    float l0 = qv[2*j] - __uint_as_float(h0);
    float l1 = qv[2*j+1] - __uint_as_float(h1);
    qhw[j] = (h0 >> 16) | h1;
    qlw[j] = (__float_as_uint(l0) >> 16) | (__float_as_uint(l1) & 0xFFFF0000u);
    u0 = __float_as_uint(kv[2*j]); u1 = __float_as_uint(kv[2*j+1]);
    h0 = u0 & 0xFFFF0000u; h1 = u1 & 0xFFFF0000u;
    l0 = kv[2*j] - __uint_as_float(h0);
    l1 = kv[2*j+1] - __uint_as_float(h1);
    khw[j] = (h0 >> 16) | h1;
    klw[j] = (__float_as_uint(l0) >> 16) | (__float_as_uint(l1) & 0xFFFF0000u);
  }
  qh[(size_t)p*2+0] = make_uint4(qhw[0], qhw[1], qhw[2], qhw[3]);
  qh[(size_t)p*2+1] = make_uint4(qhw[4], qhw[5], qhw[6], qhw[7]);
  ql[(size_t)p*2+0] = make_uint4(qlw[0], qlw[1], qlw[2], qlw[3]);
  ql[(size_t)p*2+1] = make_uint4(qlw[4], qlw[5], qlw[6], qlw[7]);
  kh[(size_t)p*2+0] = make_uint4(khw[0], khw[1], khw[2], khw[3]);
  kh[(size_t)p*2+1] = make_uint4(khw[4], khw[5], khw[6], khw[7]);
  kl[(size_t)p*2+0] = make_uint4(klw[0], klw[1], klw[2], klw[3]);
  kl[(size_t)p*2+1] = make_uint4(klw[4], klw[5], klw[6], klw[7]);
  float4 vv = ((const float4*)vpT)[p];
  vfh[0*32768 + p] = (_Float16)fmaxf(fmaf(vv.x, spr[64], spr[67]), 0.f);
  vfh[1*32768 + p] = (_Float16)fmaxf(fmaf(vv.y, spr[65], spr[68]), 0.f);
  vfh[2*32768 + p] = (_Float16)fmaxf(fmaf(vv.z, spr[66], spr[69]), 0.f);
  vfh[3*32768 + p] = (_Float16)1.0f;   // ones row -> l accumulates in PV MFMA
}

// ---- K5: swapped-operand MFMA attention, PV on MFMA, exp2 domain -----------
// QK: A = Q-side [qh;ql], B1 = [kh;kh], B2 = [kl;kl] -> exact (qh+ql)(kh+kl).
// C: col = lane&15 = n (output row, = B col); row = (lane>>4)*4+reg = m.
// Softmax: per-row M shared across the 4 k-slice lanes of same n (xor 16/32);
// defer-max THR=11.5 (log2 domain). pw -> fp16 = B-frag of P^T;
// PV: mfma_f32_16x16x16f16(A=[v0;v1;v2;ones], B=pw, acc): acc rows = a0,a1,a2,l.
// blk: cb = blk&3 (1024-col chunk), rb = blk>>2: b = rb>>7, rc = rb&127.
__global__ __launch_bounds__(128, 8) void k5_attn(
    const uint4* __restrict__ qh, const uint4* __restrict__ ql,
    const uint4* __restrict__ kh, const uint4* __restrict__ kl,
    const _Float16* __restrict__ vfh,
    float* __restrict__ pm, float* __restrict__ pl, float* __restrict__ pa0,
    float* __restrict__ pa1, float* __restrict__ pa2) {
  int tx = threadIdx.x;
  int cb = blockIdx.x & 3;
  int rb = blockIdx.x >> 2;
  int b  = rb >> 7;
  int rc = rb & 127;
  int w = tx >> 6, lane = tx & 63;
  int nl = lane & 15, g = lane >> 4, g1 = g & 1;
  int n0 = rc*32 + w*16;
  size_t pbase = (size_t)b*4096;
  size_t kp2 = (pbase + n0 + nl)*2;
  bf16x8 bKh = *(const bf16x8*)&kh[kp2 + g1];
  bf16x8 bKl = *(const bf16x8*)&kl[kp2 + g1];
  f32x4 zero4 = {0.f, 0.f, 0.f, 0.f};
  f32x4 acc = {0.f, 0.f, 0.f, 0.f};       // rows a0,a1,a2,l
  float M = 0.f;                          // per-row running max, log2 domain
  const _Float16* vrow = vfh + (size_t)nl*32768;
  bool vload = (nl < 4);
  f16x4 zeroh = {(_Float16)0.f, (_Float16)0.f, (_Float16)0.f, (_Float16)0.f};
  size_t cbase = pbase + (size_t)cb*1024;
  #pragma unroll 2
  for (int ct = 0; ct < 64; ++ct) {
    size_t qp2 = (cbase + ct*16 + nl)*2;
    bf16x8 aQ = (g < 2) ? *(const bf16x8*)&qh[qp2 + g1]
                        : *(const bf16x8*)&ql[qp2 + g1];
    f32x4 c = __builtin_amdgcn_mfma_f32_16x16x32_bf16(aQ, bKh, zero4, 0, 0, 0);
    c = __builtin_amdgcn_mfma_f32_16x16x32_bf16(aQ, bKl, c, 0, 0, 0);
    float cmax = fmaxf(fmaxf(c[0], c[1]), fmaxf(c[2], c[3]));
    cmax = fmaxf(cmax, __shfl_xor(cmax, 16));
    cmax = fmaxf(cmax, __shfl_xor(cmax, 32));
    if (cmax - M > 11.5f) {               // rare per-row rescale (defer-max)
      float cc = exp2f(M - cmax);
      acc[0] *= cc; acc[1] *= cc; acc[2] *= cc; acc[3] *= cc;
      M = cmax;
    }
    f16x4 pw;
    pw[0] = (_Float16)exp2f(c[0] - M);
    pw[1] = (_Float16)exp2f(c[1] - M);
    pw[2] = (_Float16)exp2f(c[2] - M);
    pw[3] = (_Float16)exp2f(c[3] - M);
    f16x4 av = zeroh;
    if (vload) av = *(const f16x4*)&vrow[cbase + ct*16 + g*4];
    acc = __builtin_amdgcn_mfma_f32_16x16x16f16(av, pw, acc, 0, 0, 0);
  }
  if (lane < 16) {
    size_t base = (size_t)cb*32768 + pbase + n0 + lane;
    pm[base] = M; pl[base] = acc[3];
    pa0[base] = acc[0]; pa1[base] = acc[1]; pa2[base] = acc[2];
  }
}

// ---- K6: max-merge 4 column-chunk partials (log2 domain) + epilogue --------
__global__ __launch_bounds__(256) void k6_merge(
    const float* __restrict__ pm, const float* __restrict__ pl,
    const float* __restrict__ pa0, const float* __restrict__ pa1,
    const float* __restrict__ pa2, const float* __restrict__ x,
    const float* __restrict__ alpha, float* __restrict__ out) {
  int row = blockIdx.x*256 + threadIdx.x;   // 0..32767
  float m0 = pm[row],           m1 = pm[32768+row];
  float m2 = pm[2*32768+row],   m3 = pm[3*32768+row];
  float M = fmaxf(fmaxf(m0, m1), fmaxf(m2, m3));
  float c0 = exp2f(m0 - M), c1 = exp2f(m1 - M);
  float c2 = exp2f(m2 - M), c3 = exp2f(m3 - M);
  float L  = pl[row]*c0  + pl[32768+row]*c1  + pl[2*32768+row]*c2  + pl[3*32768+row]*c3;
  float A0 = pa0[row]*c0 + pa0[32768+row]*c1 + pa0[2*32768+row]*c2 + pa0[3*32768+row]*c3;
  float A1 = pa1[row]*c0 + pa1[32768+row]*c1 + pa1[2*32768+row]*c2 + pa1[3*32768+row]*c3;
  float A2 = pa2[row]*c0 + pa2[32768+row]*c1 + pa2[2*32768+row]*c2 + pa2[3*32768+row]*c3;
  int b = row >> 12, n = row & 4095;
  float inv = 1.f / L, al = alpha[0];
  out[(size_t)(b*3+0)*NN + n] = fmaf(al, A0*inv, x[(size_t)(b*3+0)*NN + n]);
  out[(size_t)(b*3+1)*NN + n] = fmaf(al, A1*inv, x[(size_t)(b*3+1)*NN + n]);
  out[(size_t)(b*3+2)*NN + n] = fmaf(al, A2*inv, x[(size_t)(b*3+2)*NN + n]);
}

extern "C" void kernel_launch(void* const* d_in, const int* in_sizes, int n_in,
                              void* d_out, int out_size, void* d_ws, size_t ws_size,
                              hipStream_t stream) {
  const float* x    = (const float*)d_in[0];
  const float* w1   = (const float*)d_in[1];
  const float* g1   = (const float*)d_in[2];
  const float* b1   = (const float*)d_in[3];
  const float* w2   = (const float*)d_in[4];
  const float* wq   = (const float*)d_in[5];
  const float* g2   = (const float*)d_in[6];
  const float* b2   = (const float*)d_in[7];
  const float* wk   = (const float*)d_in[8];
  const float* g3   = (const float*)d_in[9];
  const float* b3   = (const float*)d_in[10];
  const float* wv   = (const float*)d_in[11];
  const float* g4   = (const float*)d_in[12];
  const float* b4   = (const float*)d_in[13];
  const float* alpha= (const float*)d_in[14];
  float* out = (float*)d_out;
  float* ws  = (float*)d_ws;

  float* qpT = ws + OFF_QPT;
  float* kpT = ws + OFF_KPT;
  float* vpT = ws + OFF_VPT;
  float* wt2 = ws + OFF_WT2;
  float* xp  = ws + OFF_XP;
  float* bst = ws + OFF_BS;
  uint4* qhb = (uint4*)(ws + OFF_QH);
  uint4* qlb = (uint4*)(ws + OFF_QL);
  uint4* khb = (uint4*)(ws + OFF_KH);
  uint4* klb = (uint4*)(ws + OFF_KL);
  _Float16* vfh = (_Float16*)(ws + OFF_VFH);
  float* pls = ws + OFF_PL;
  float* pa0 = ws + OFF_PA0;
  float* pa1 = ws + OFF_PA1;
  float* pa2 = ws + OFF_PA2;
  float* pms = ws + OFF_PM;

  kA_mom_wcomb<<<129, 256, 0, stream>>>(x, xp, w2, wq, wk, wv, wt2);
  kB_qkv<<<256, 128, 0, stream>>>(x, xp, w1, g1, b1, wt2, qpT, kpT, vpT, bst);
  kC_prep<<<128, 256, 0, stream>>>(qpT, kpT, vpT, bst, g2, b2, g3, b3, g4, b4,
                                   qhb, qlb, khb, klb, vfh);
  k5_attn<<<4096, 128, 0, stream>>>(qhb, qlb, khb, klb, vfh, pms, pls, pa0, pa1, pa2);
  k6_merge<<<128, 256, 0, stream>>>(pms, pls, pa0, pa1, pa2, x, alpha, out);
}

// Round 13
// 101.738 us; speedup vs baseline: 11.0499x; 1.1922x over previous
//
#include <hip/hip_runtime.h>

#define EPS 1e-5f
constexpr int NN = 4096;
constexpr float INV_CNT = 1.0f / (8.0f * 4096.0f);
constexpr float LOG2E = 1.44269504f;

typedef __attribute__((ext_vector_type(8))) short bf16x8;
typedef __attribute__((ext_vector_type(4))) float f32x4;
typedef __attribute__((ext_vector_type(4))) _Float16 f16x4;
typedef __fp16 fp16x2 __attribute__((ext_vector_type(2)));

#if __has_builtin(__builtin_amdgcn_exp2f)
#define EXP2F(x) __builtin_amdgcn_exp2f(x)
#else
#define EXP2F(x) exp2f(x)
#endif

// workspace layout (float offsets)
constexpr size_t OFF_QPT = 0;        // 524288  q pre-act, point-major [p][16]
constexpr size_t OFF_KPT = 524288;   // 524288
constexpr size_t OFF_VPT = 1048576;  // 131072  v pre-act, [p][4]
constexpr size_t OFF_WT2 = 1179648;  // 2304
constexpr size_t OFF_XP  = 1181952;  // 1152
constexpr size_t OFF_BS  = 1183104;  // 70*256 = 17920
constexpr size_t OFF_QH  = 1201024;  // 262144 (bf16 hi, [p][16] = 2 uint4/p)
constexpr size_t OFF_QL  = 1463168;  // 262144
constexpr size_t OFF_KH  = 1725312;  // 262144
constexpr size_t OFF_KL  = 1987456;  // 262144
constexpr size_t OFF_VFH = 2249600;  // 65536 fl = 4ch x 32768 fp16 (v0,v1,v2,ones)
constexpr size_t OFF_PL  = 2315136;  // 4*32768
constexpr size_t OFF_PA0 = 2446208;
constexpr size_t OFF_PA1 = 2577280;
constexpr size_t OFF_PA2 = 2708352;
constexpr size_t OFF_PM  = 2839424;  // 4*32768; end 2970496 = 11.9 MB

// ---- kA: blocks 0-127: x moments; block 128: combined weights --------------
__global__ __launch_bounds__(256) void kA_mom_wcomb(
    const float* __restrict__ x, float* __restrict__ xpart,
    const float* __restrict__ w2, const float* __restrict__ wq,
    const float* __restrict__ wk, const float* __restrict__ wv,
    float* __restrict__ wt2) {
  __shared__ float w2s[8192];
  __shared__ float wr[4480];
  __shared__ float sred[36];
  int tx = threadIdx.x;
  if (blockIdx.x < 128) {
    int idx = blockIdx.x * 256 + tx;
    int b = idx >> 12, n = idx & 4095;
    float x0 = x[(size_t)(b*3+0)*NN + n];
    float x1 = x[(size_t)(b*3+1)*NN + n];
    float x2 = x[(size_t)(b*3+2)*NN + n];
    float m[9] = {x0, x1, x2, x0*x0, x0*x1, x0*x2, x1*x1, x1*x2, x2*x2};
    #pragma unroll
    for (int off = 32; off; off >>= 1) {
      #pragma unroll
      for (int j = 0; j < 9; ++j) m[j] += __shfl_xor(m[j], off);
    }
    int w = tx >> 6;
    if ((tx & 63) == 0) {
      #pragma unroll
      for (int j = 0; j < 9; ++j) sred[w*9+j] = m[j];
    }
    __syncthreads();
    if (tx < 9) xpart[tx*128 + blockIdx.x] = sred[tx] + sred[9+tx] + sred[18+tx] + sred[27+tx];
  } else {
    for (int i = tx; i < 8192; i += 256) w2s[i] = w2[i];
    for (int i = tx; i < 2048; i += 256) { wr[i] = wq[i]; wr[2048+i] = wk[i]; }
    for (int i = tx; i < 384; i += 256) wr[4096+i] = wv[i];
    __syncthreads();
    for (int e = tx; e < 2240; e += 256) {
      int j = e >> 6, c = e & 63;
      float s = 0.f;
      #pragma unroll 4
      for (int o = 0; o < 128; ++o) s = fmaf(wr[j*128+o], w2s[o*64+c], s);
      wt2[c*36 + j] = s;
    }
  }
}

// ---- kB: (f1 fused) per point -> qa/ka/va + block-partial stats ------------
__global__ __launch_bounds__(128) void kB_qkv(
    const float* __restrict__ x, const float* __restrict__ xpart,
    const float* __restrict__ w1, const float* __restrict__ g1,
    const float* __restrict__ b1, const float* __restrict__ wt2,
    float* __restrict__ qpT, float* __restrict__ kpT, float* __restrict__ vpT,
    float* __restrict__ bs) {
  __shared__ float4 w1s[64];
  __shared__ float4 wt2s[576];
  __shared__ float sred[140];
  __shared__ float mom[9];
  int tx = threadIdx.x;
  for (int i = tx; i < 576; i += 128) wt2s[i] = ((const float4*)wt2)[i];
  if (tx < 9) {
    float acc = 0.f;
    #pragma unroll 8
    for (int i = 0; i < 128; ++i) acc += xpart[tx*128 + i];
    mom[tx] = acc * INV_CNT;
  }
  __syncthreads();
  if (tx < 64) {
    int c = tx;
    float a = w1[c*3], b_ = w1[c*3+1], d = w1[c*3+2];
    float mean = a*mom[0] + b_*mom[1] + d*mom[2];
    float e2 = a*a*mom[3] + b_*b_*mom[6] + d*d*mom[8]
             + 2.f*(a*b_*mom[4] + a*d*mom[5] + b_*d*mom[7]);
    float sc = g1[c] * rsqrtf(e2 - mean*mean + EPS);
    w1s[c] = make_float4(a*sc, b_*sc, d*sc, fmaf(-mean, sc, b1[c]));
  }
  __syncthreads();
  int idx = blockIdx.x*128 + tx;
  int b = idx >> 12, n = idx & 4095;
  float x0 = x[(size_t)(b*3+0)*NN + n];
  float x1 = x[(size_t)(b*3+1)*NN + n];
  float x2 = x[(size_t)(b*3+2)*NN + n];
  float qa[16] = {}, ka[16] = {};
  float va0 = 0.f, va1 = 0.f, va2 = 0.f;
  #pragma unroll 4
  for (int c = 0; c < 64; ++c) {
    float4 w = w1s[c];
    float h = fmaf(w.x, x0, fmaf(w.y, x1, fmaf(w.z, x2, w.w)));
    h = h > 0.f ? h : 0.2f*h;
    #pragma unroll
    for (int j = 0; j < 4; ++j) {
      float4 A = wt2s[c*9 + j];
      qa[4*j+0] = fmaf(A.x, h, qa[4*j+0]);
      qa[4*j+1] = fmaf(A.y, h, qa[4*j+1]);
      qa[4*j+2] = fmaf(A.z, h, qa[4*j+2]);
      qa[4*j+3] = fmaf(A.w, h, qa[4*j+3]);
      float4 B = wt2s[c*9 + 4 + j];
      ka[4*j+0] = fmaf(B.x, h, ka[4*j+0]);
      ka[4*j+1] = fmaf(B.y, h, ka[4*j+1]);
      ka[4*j+2] = fmaf(B.z, h, ka[4*j+2]);
      ka[4*j+3] = fmaf(B.w, h, ka[4*j+3]);
    }
    float4 V = wt2s[c*9 + 8];
    va0 = fmaf(V.x, h, va0); va1 = fmaf(V.y, h, va1); va2 = fmaf(V.z, h, va2);
  }
  float4* qo = (float4*)(qpT + (size_t)idx*16);
  float4* ko = (float4*)(kpT + (size_t)idx*16);
  #pragma unroll
  for (int j = 0; j < 4; ++j) {
    qo[j] = make_float4(qa[4*j], qa[4*j+1], qa[4*j+2], qa[4*j+3]);
    ko[j] = make_float4(ka[4*j], ka[4*j+1], ka[4*j+2], ka[4*j+3]);
  }
  ((float4*)vpT)[idx] = make_float4(va0, va1, va2, 0.f);
  int w = tx >> 6;
  bool lead = ((tx & 63) == 0);
  #pragma unroll
  for (int d = 0; d < 16; ++d) {
    float s = qa[d], q = qa[d]*qa[d];
    #pragma unroll
    for (int off = 32; off; off >>= 1) { s += __shfl_xor(s, off); q += __shfl_xor(q, off); }
    if (lead) { sred[w*70 + d] = s; sred[w*70 + 16 + d] = q; }
    s = ka[d]; q = ka[d]*ka[d];
    #pragma unroll
    for (int off = 32; off; off >>= 1) { s += __shfl_xor(s, off); q += __shfl_xor(q, off); }
    if (lead) { sred[w*70 + 32 + d] = s; sred[w*70 + 48 + d] = q; }
  }
  float vv[3] = {va0, va1, va2};
  #pragma unroll
  for (int d = 0; d < 3; ++d) {
    float s = vv[d], q = vv[d]*vv[d];
    #pragma unroll
    for (int off = 32; off; off >>= 1) { s += __shfl_xor(s, off); q += __shfl_xor(q, off); }
    if (lead) { sred[w*70 + 64 + d] = s; sred[w*70 + 67 + d] = q; }
  }
  __syncthreads();
  if (tx < 70)
    bs[tx*256 + blockIdx.x] = sred[tx] + sred[70+tx];
}

// ---- kC: (f2 fused) BN+ReLU, q scaled by log2e, hi/lo split, v->fp16 -------
__global__ __launch_bounds__(256) void kC_prep(
    const float* __restrict__ qpT, const float* __restrict__ kpT,
    const float* __restrict__ vpT, const float* __restrict__ bs,
    const float* __restrict__ g2, const float* __restrict__ b2,
    const float* __restrict__ g3, const float* __restrict__ b3,
    const float* __restrict__ g4, const float* __restrict__ b4,
    uint4* __restrict__ qh, uint4* __restrict__ ql,
    uint4* __restrict__ kh, uint4* __restrict__ kl,
    _Float16* __restrict__ vfh) {
  __shared__ float tot[70];
  __shared__ float spr[70];
  int tx = threadIdx.x;
  if (tx < 70) {
    float acc = 0.f;
    #pragma unroll 8
    for (int i = 0; i < 256; ++i) acc += bs[tx*256 + i];
    tot[tx] = acc * INV_CNT;
  }
  __syncthreads();
  if (tx < 16) {
    float mean = tot[tx], var = tot[16+tx] - mean*mean;
    float sc = g2[tx]*rsqrtf(var + EPS);
    spr[tx] = sc * LOG2E;                                // q scaled to log2 domain
    spr[16+tx] = fmaf(-mean, sc, b2[tx]) * LOG2E;
  } else if (tx < 32) {
    int d = tx-16;
    float mean = tot[32+d], var = tot[48+d] - mean*mean;
    float sc = g3[d]*rsqrtf(var + EPS);
    spr[32+d] = sc; spr[48+d] = fmaf(-mean, sc, b3[d]);
  } else if (tx < 35) {
    int d = tx-32;
    float mean = tot[64+d], var = tot[67+d] - mean*mean;
    float sc = g4[d]*rsqrtf(var + EPS);
    spr[64+d] = sc; spr[67+d] = fmaf(-mean, sc, b4[d]);
  }
  __syncthreads();
  int p = blockIdx.x*256 + tx;
  float qv[16], kv[16];
  const float4* q4 = (const float4*)(qpT + (size_t)p*16);
  const float4* k4p = (const float4*)(kpT + (size_t)p*16);
  #pragma unroll
  for (int j = 0; j < 4; ++j) {
    float4 tq = q4[j], tk = k4p[j];
    qv[4*j] = tq.x; qv[4*j+1] = tq.y; qv[4*j+2] = tq.z; qv[4*j+3] = tq.w;
    kv[4*j] = tk.x; kv[4*j+1] = tk.y; kv[4*j+2] = tk.z; kv[4*j+3] = tk.w;
  }
  #pragma unroll
  for (int d = 0; d < 16; ++d) {
    qv[d] = fmaxf(fmaf(qv[d], spr[d],    spr[16+d]), 0.f);
    kv[d] = fmaxf(fmaf(kv[d], spr[32+d], spr[48+d]), 0.f);
  }
  unsigned qhw[8], qlw[8], khw[8], klw[8];
  #pragma unroll
  for (int j = 0; j < 8; ++j) {
    unsigned u0 = __float_as_uint(qv[2*j]),   u1 = __float_as_uint(qv[2*j+1]);
    unsigned h0 = u0 & 0xFFFF0000u, h1 = u1 & 0xFFFF0000u;
    float l0 = qv[2*j] - __uint_as_float(h0);
    float l1 = qv[2*j+1] - __uint_as_float(h1);
    qhw[j] = (h0 >> 16) | h1;
    qlw[j] = (__float_as_uint(l0) >> 16) | (__float_as_uint(l1) & 0xFFFF0000u);
    u0 = __float_as_uint(kv[2*j]); u1 = __float_as_uint(kv[2*j+1]);
    h0 = u0 & 0xFFFF0000u; h1 = u1 & 0xFFFF0000u;
    l0 = kv[2*j] - __uint_as_float(h0);
    l1 = kv[2*j+1] - __uint_as_float(h1);
    khw[j] = (h0 >> 16) | h1;
    klw[j] = (__float_as_uint(l0) >> 16) | (__float_as_uint(l1) & 0xFFFF0000u);
  }
  qh[(size_t)p*2+0] = make_uint4(qhw[0], qhw[1], qhw[2], qhw[3]);
  qh[(size_t)p*2+1] = make_uint4(qhw[4], qhw[5], qhw[6], qhw[7]);
  ql[(size_t)p*2+0] = make_uint4(qlw[0], qlw[1], qlw[2], qlw[3]);
  ql[(size_t)p*2+1] = make_uint4(qlw[4], qlw[5], qlw[6], qlw[7]);
  kh[(size_t)p*2+0] = make_uint4(khw[0], khw[1], khw[2], khw[3]);
  kh[(size_t)p*2+1] = make_uint4(khw[4], khw[5], khw[6], khw[7]);
  kl[(size_t)p*2+0] = make_uint4(klw[0], klw[1], klw[2], klw[3]);
  kl[(size_t)p*2+1] = make_uint4(klw[4], klw[5], klw[6], klw[7]);
  float4 vv = ((const float4*)vpT)[p];
  vfh[0*32768 + p] = (_Float16)fmaxf(fmaf(vv.x, spr[64], spr[67]), 0.f);
  vfh[1*32768 + p] = (_Float16)fmaxf(fmaf(vv.y, spr[65], spr[68]), 0.f);
  vfh[2*32768 + p] = (_Float16)fmaxf(fmaf(vv.z, spr[66], spr[69]), 0.f);
  vfh[3*32768 + p] = (_Float16)1.0f;   // ones row -> l accumulates in PV MFMA
}

// ---- K5: swapped-operand MFMA attention, PV on MFMA, lean codegen ----------
// QK: A = Q-side [qh;ql], B1 = [kh;kh], B2 = [kl;kl] -> exact (qh+ql)(kh+kl).
// C: col = lane&15 = n; row = (lane>>4)*4+reg = m. Per-row M shared across the
// 4 g-lanes (xor 16/32); branchless always-rescale (exp args <= 0, fp16-safe).
// pw via v_cvt_pkrtz; PV: mfma_f32_16x16x16f16(A=[v0;v1;v2;ones], B=pw, acc).
// blk: cb = blk&3 (1024-col chunk), rb = blk>>2: b = rb>>7, rc = rb&127.
__global__ __launch_bounds__(128, 8) void k5_attn(
    const uint4* __restrict__ qh, const uint4* __restrict__ ql,
    const uint4* __restrict__ kh, const uint4* __restrict__ kl,
    const _Float16* __restrict__ vfh,
    float* __restrict__ pm, float* __restrict__ pl, float* __restrict__ pa0,
    float* __restrict__ pa1, float* __restrict__ pa2) {
  int tx = threadIdx.x;
  int cb = blockIdx.x & 3;
  int rb = blockIdx.x >> 2;
  int b  = rb >> 7;
  int rc = rb & 127;
  int w = tx >> 6, lane = tx & 63;
  int nl = lane & 15, g = lane >> 4, g1 = g & 1;
  int n0 = rc*32 + w*16;
  size_t pbase = (size_t)b*4096;
  size_t kp2 = (pbase + n0 + nl)*2;
  bf16x8 bKh = *(const bf16x8*)&kh[kp2 + g1];
  bf16x8 bKl = *(const bf16x8*)&kl[kp2 + g1];
  f32x4 zero4 = {0.f, 0.f, 0.f, 0.f};
  f32x4 acc = {0.f, 0.f, 0.f, 0.f};       // rows a0,a1,a2,l
  float M = 0.f;                          // per-row running max, log2 domain
  size_t cbase = pbase + (size_t)cb*1024;
  // hoisted select + pointer-increment addressing (no per-iter 64b arith)
  const uint4* qptr = ((g < 2) ? qh : ql) + (cbase + nl)*2 + g1;
  const _Float16* vptr = vfh + (size_t)nl*32768 + cbase + g*4;
  bool vload = (nl < 4);
  f16x4 zeroh = {(_Float16)0.f, (_Float16)0.f, (_Float16)0.f, (_Float16)0.f};
  #pragma unroll 4
  for (int ct = 0; ct < 64; ++ct) {
    bf16x8 aQ = *(const bf16x8*)qptr;
    qptr += 32;                           // 16 points x 2 uint4
    f32x4 c = __builtin_amdgcn_mfma_f32_16x16x32_bf16(aQ, bKh, zero4, 0, 0, 0);
    c = __builtin_amdgcn_mfma_f32_16x16x32_bf16(aQ, bKl, c, 0, 0, 0);
    float cmax = fmaxf(fmaxf(c[0], c[1]), fmaxf(c[2], c[3]));
    cmax = fmaxf(cmax, __shfl_xor(cmax, 16));
    cmax = fmaxf(cmax, __shfl_xor(cmax, 32));
    float Mn = fmaxf(M, cmax);            // branchless online max
    float cc = EXP2F(M - Mn);
    acc[0] *= cc; acc[1] *= cc; acc[2] *= cc; acc[3] *= cc;
    M = Mn;
    union { fp16x2 h2[2]; f16x4 v4; } pw;
    pw.h2[0] = __builtin_amdgcn_cvt_pkrtz(EXP2F(c[0] - M), EXP2F(c[1] - M));
    pw.h2[1] = __builtin_amdgcn_cvt_pkrtz(EXP2F(c[2] - M), EXP2F(c[3] - M));
    f16x4 av = zeroh;
    if (vload) av = *(const f16x4*)vptr;
    vptr += 16;
    acc = __builtin_amdgcn_mfma_f32_16x16x16f16(av, pw.v4, acc, 0, 0, 0);
  }
  if (lane < 16) {
    size_t base = (size_t)cb*32768 + pbase + n0 + lane;
    pm[base] = M; pl[base] = acc[3];
    pa0[base] = acc[0]; pa1[base] = acc[1]; pa2[base] = acc[2];
  }
}

// ---- K6: max-merge 4 column-chunk partials (log2 domain) + epilogue --------
__global__ __launch_bounds__(256) void k6_merge(
    const float* __restrict__ pm, const float* __restrict__ pl,
    const float* __restrict__ pa0, const float* __restrict__ pa1,
    const float* __restrict__ pa2, const float* __restrict__ x,
    const float* __restrict__ alpha, float* __restrict__ out) {
  int row = blockIdx.x*256 + threadIdx.x;   // 0..32767
  float m0 = pm[row],           m1 = pm[32768+row];
  float m2 = pm[2*32768+row],   m3 = pm[3*32768+row];
  float M = fmaxf(fmaxf(m0, m1), fmaxf(m2, m3));
  float c0 = exp2f(m0 - M), c1 = exp2f(m1 - M);
  float c2 = exp2f(m2 - M), c3 = exp2f(m3 - M);
  float L  = pl[row]*c0  + pl[32768+row]*c1  + pl[2*32768+row]*c2  + pl[3*32768+row]*c3;
  float A0 = pa0[row]*c0 + pa0[32768+row]*c1 + pa0[2*32768+row]*c2 + pa0[3*32768+row]*c3;
  float A1 = pa1[row]*c0 + pa1[32768+row]*c1 + pa1[2*32768+row]*c2 + pa1[3*32768+row]*c3;
  float A2 = pa2[row]*c0 + pa2[32768+row]*c1 + pa2[2*32768+row]*c2 + pa2[3*32768+row]*c3;
  int b = row >> 12, n = row & 4095;
  float inv = 1.f / L, al = alpha[0];
  out[(size_t)(b*3+0)*NN + n] = fmaf(al, A0*inv, x[(size_t)(b*3+0)*NN + n]);
  out[(size_t)(b*3+1)*NN + n] = fmaf(al, A1*inv, x[(size_t)(b*3+1)*NN + n]);
  out[(size_t)(b*3+2)*NN + n] = fmaf(al, A2*inv, x[(size_t)(b*3+2)*NN + n]);
}

extern "C" void kernel_launch(void* const* d_in, const int* in_sizes, int n_in,
                              void* d_out, int out_size, void* d_ws, size_t ws_size,
                              hipStream_t stream) {
  const float* x    = (const float*)d_in[0];
  const float* w1   = (const float*)d_in[1];
  const float* g1   = (const float*)d_in[2];
  const float* b1   = (const float*)d_in[3];
  const float* w2   = (const float*)d_in[4];
  const float* wq   = (const float*)d_in[5];
  const float* g2   = (const float*)d_in[6];
  const float* b2   = (const float*)d_in[7];
  const float* wk   = (const float*)d_in[8];
  const float* g3   = (const float*)d_in[9];
  const float* b3   = (const float*)d_in[10];
  const float* wv   = (const float*)d_in[11];
  const float* g4   = (const float*)d_in[12];
  const float* b4   = (const float*)d_in[13];
  const float* alpha= (const float*)d_in[14];
  float* out = (float*)d_out;
  float* ws  = (float*)d_ws;

  float* qpT = ws + OFF_QPT;
  float* kpT = ws + OFF_KPT;
  float* vpT = ws + OFF_VPT;
  float* wt2 = ws + OFF_WT2;
  float* xp  = ws + OFF_XP;
  float* bst = ws + OFF_BS;
  uint4* qhb = (uint4*)(ws + OFF_QH);
  uint4* qlb = (uint4*)(ws + OFF_QL);
  uint4* khb = (uint4*)(ws + OFF_KH);
  uint4* klb = (uint4*)(ws + OFF_KL);
  _Float16* vfh = (_Float16*)(ws + OFF_VFH);
  float* pls = ws + OFF_PL;
  float* pa0 = ws + OFF_PA0;
  float* pa1 = ws + OFF_PA1;
  float* pa2 = ws + OFF_PA2;
  float* pms = ws + OFF_PM;

  kA_mom_wcomb<<<129, 256, 0, stream>>>(x, xp, w2, wq, wk, wv, wt2);
  kB_qkv<<<256, 128, 0, stream>>>(x, xp, w1, g1, b1, wt2, qpT, kpT, vpT, bst);
  kC_prep<<<128, 256, 0, stream>>>(qpT, kpT, vpT, bst, g2, b2, g3, b3, g4, b4,
                                   qhb, qlb, khb, klb, vfh);
  k5_attn<<<4096, 128, 0, stream>>>(qhb, qlb, khb, klb, vfh, pms, pls, pa0, pa1, pa2);
  k6_merge<<<128, 256, 0, stream>>>(pms, pls, pa0, pa1, pa2, x, alpha, out);
}